// Round 8
// baseline (2736.206 us; speedup 1.0000x reference)
//
#include <hip/hip_runtime.h>
#include <math.h>

// CoGNN forward. Round 37 (best = r36 2654us). prop4 still latency-bound
// (VALU 16.5%, HBM 9.7%, Occ 55%). Change: prop4 blocks 256->512 threads
// at same CH_BLK=4 / 32KB LDS -> 4 blocks x 8 waves = 32 waves/CU (HW cap,
// was 20) AND half the blocks -> per-CU edge-meta L1/L2 traffic halves.
// Per-thread hop loops 4->2 iters; CSC snake = 2 rounds x 8 waves pairing
// tile t with 15-t. k_norm -> grid-stride 2048 blocks (was up to 52K tiny
// blocks). Everything else = r36 (li0 folding, shfl topk, per-lane float4
// gathers, pure powers P1,P2,Q1,Q2, alpha folded into k_mix).
// B=32,C=32,V=1000,L:19->13->7->1. fp32.

#define ALPHA_C 0.05f
#define EPS_C 1e-5f
#define NBC 32
#define CSCT_CAP 140000

// ---------------- static device workspace ----------------
__device__ float g_inp[32 * 19 * 1000];
__device__ float g_skip[32 * 64 * 1000];
__device__ float g_nv1[240000];
__device__ float g_nv2[240000];
__device__ __align__(16) int   g_tkcol[60000];
__device__ __align__(16) float g_tkval[60000];
__device__ float g_inv1[3000];
__device__ int   g_colcnt[3000];
__device__ float g_colsum[3000];
__device__ int   g_rp2[3 * 1001 + 1];
__device__ int   g_fill[3000];
__device__ int   g_cscr[60000];
__device__ float g_cscv[60000];
__device__ float g_inv2[3000];
__device__ float g_stats[3 * 64];
__device__ __align__(16) int2 g_pk1T[60000];        // CSR transposed [li][j][v] = (col*16, w)
__device__ __align__(16) int2 g_cscT[3 * CSCT_CAP]; // CSC tiled-transposed (row*16, w)
__device__ int   g_perm[3 * 1024];   // [li][rank] -> v (global degree desc; -1 sentinel)
__device__ int   g_degT[3 * 1024];   // [li][rank] -> degree
__device__ int   g_iperm[3 * 1000];  // [li][v] -> rank
__device__ int   g_tOff[3 * 17];     // [li][tile] -> cscT base offset
__device__ float g_B0[(size_t)NBC * 32 * 19 * 1000];
__device__ float g_B1[(size_t)NBC * 32 * 19 * 1000];
__device__ float g_B2[(size_t)NBC * 32 * 19 * 1000];
__device__ float g_B3[(size_t)NBC * 32 * 19 * 1000];
__device__ float g_B4[(size_t)NBC * 32 * 19 * 1000];
__device__ float g_B5[(size_t)NBC * 32 * 19 * 1000];

__device__ __forceinline__ float* bufsel(int s)
{
    switch (s) {
        case 0: return g_B0;
        case 1: return g_B1;
        case 2: return g_B2;
        case 3: return g_B3;
        case 4: return g_B4;
        default: return g_B5;
    }
}

__global__ void k_init()
{
    int i = blockIdx.x * 256 + threadIdx.x;
    if (i < 3000) { g_colcnt[i] = 0; g_colsum[i] = 0.f; g_fill[i] = 0; }
    if (i < 192) g_stats[i] = 0.f;
}

__global__ void k_out_zero(float* __restrict__ out, int n)
{
    int i = blockIdx.x * 256 + threadIdx.x;
    if (i < n) out[i] = 0.0f;
}

__global__ void k_marker(float* __restrict__ out, float v)
{
    if (threadIdx.x == 0) out[0] = v;
}

// ---------------- setup ----------------

__global__ void k_build_inp(const float* __restrict__ xin)
{
    int i = blockIdx.x * 256 + threadIdx.x;
    if (i >= 32 * 19 * 1000) return;
    int v = i % 1000;
    int t = (i / 1000) % 19;
    int b = i / 19000;
    float val = 0.f;
    if (t >= 7) {
        int tt = t - 7;
        int n = (v < 500) ? v : v - 500;
        int f = (v < 500) ? 0 : 1;
        val = xin[((b * 12 + tt) * 500 + n) * 4 + f];
    }
    g_inp[i] = val;
}

__global__ void k_nv(const float* __restrict__ e1, const float* __restrict__ e2,
                     const float* __restrict__ w1, const float* __restrict__ b1,
                     const float* __restrict__ w2, const float* __restrict__ b2)
{
    int i = blockIdx.x * 256 + threadIdx.x;
    if (i >= 12 * 500 * 40) return;
    int o = i % 40;
    int n = (i / 40) % 500;
    int m = i / (40 * 500);
    const float* p1 = e1 + (m * 500 + n) * 40;
    const float* pw1 = w1 + (m * 40 + o) * 40;
    const float* p2 = e2 + (m * 500 + n) * 40;
    const float* pw2 = w2 + (m * 40 + o) * 40;
    float a1 = b1[m * 40 + o], a2 = b2[m * 40 + o];
    for (int d = 0; d < 40; ++d) {
        a1 += p1[d] * pw1[d];
        a2 += p2[d] * pw2[d];
    }
    g_nv1[i] = a1;
    g_nv2[i] = a2;
}

__global__ __launch_bounds__(256) void k_adj_topk()
{
    __shared__ float row[1000];
    __shared__ float wvv[4];
    __shared__ int wvi[4];
    __shared__ int selc[20];
    __shared__ float selv[20];
    int li = blockIdx.x / 1000;
    int r = blockIdx.x % 1000;
    int tid = threadIdx.x;
    int wv = tid >> 6, lane = tid & 63;
    int bi = r / 500, n = r % 500;
    for (int c = tid; c < 1000; c += 256) {
        int bj = c / 500, k = c % 500;
        int mg = li * 4 + 2 * bi + bj;
        const float* a = g_nv1 + (mg * 500 + n) * 40;
        const float* b = g_nv2 + (mg * 500 + k) * 40;
        float acc = 0.f;
#pragma unroll
        for (int d = 0; d < 40; ++d) acc += a[d] * b[d];
        row[c] = acc;
    }
    __syncthreads();
    for (int sel = 0; sel < 20; ++sel) {
        float bv = -INFINITY;
        int bidx = 0;
        for (int c = tid; c < 1000; c += 256) {
            float x = row[c];
            if (x > bv) { bv = x; bidx = c; }
        }
#pragma unroll
        for (int m = 1; m < 64; m <<= 1) {
            float ov = __shfl_xor(bv, m);
            int oi = __shfl_xor(bidx, m);
            if (ov > bv || (ov == bv && oi < bidx)) { bv = ov; bidx = oi; }
        }
        if (lane == 0) { wvv[wv] = bv; wvi[wv] = bidx; }
        __syncthreads();
        if (tid == 0) {
            float fv = wvv[0];
            int fi = wvi[0];
#pragma unroll
            for (int k = 1; k < 4; ++k) {
                float ov = wvv[k];
                int oi = wvi[k];
                if (ov > fv || (ov == fv && oi < fi)) { fv = ov; fi = oi; }
            }
            int ci = fi;
            if (ci < 0 || ci > 999) ci = sel;
            selc[sel] = ci;
            selv[sel] = fv;
            g_tkcol[(li * 1000 + r) * 20 + sel] = ci;
            g_tkval[(li * 1000 + r) * 20 + sel] = fv;
            row[ci] = -INFINITY;
        }
        __syncthreads();
    }
    if (tid < 20) {
        atomicAdd(&g_colcnt[li * 1000 + selc[tid]], 1);
        atomicAdd(&g_colsum[li * 1000 + selc[tid]], selv[tid]);
    }
    if (tid == 0) {
        float s = 0.f;
        for (int j = 0; j < 20; ++j) s += selv[j];
        g_inv1[li * 1000 + r] = 1.f / (s + 1.f);
    }
}

__global__ __launch_bounds__(256) void k_scan()
{
    __shared__ int s[1000];
    int li = blockIdx.x;
    int tid = threadIdx.x;
    for (int i = tid; i < 1000; i += 256) s[i] = g_colcnt[li * 1000 + i];
    __syncthreads();
    if (tid == 0) {
        int run = 0;
        for (int i = 0; i < 1000; ++i) { int c = s[i]; s[i] = run; run += c; }
        g_rp2[li * 1001 + 1000] = run;
    }
    __syncthreads();
    for (int i = tid; i < 1000; i += 256) {
        g_rp2[li * 1001 + i] = s[i];
        g_inv2[li * 1000 + i] = 1.f / (g_colsum[li * 1000 + i] + 1.f);
    }
}

// global exact degree rank sort (desc, ties by index) + tile offsets
__global__ __launch_bounds__(256) void k_permsort()
{
    __shared__ int deg[1000];
    __shared__ int tmax[16];
    int li = blockIdx.x;
    int tid = threadIdx.x;
    for (int v = tid; v < 1000; v += 256)
        deg[v] = g_rp2[li * 1001 + v + 1] - g_rp2[li * 1001 + v];
    __syncthreads();
    for (int v = tid; v < 1000; v += 256) {
        int d = deg[v];
        int r = 0;
        for (int u = 0; u < 1000; ++u) {
            int du = deg[u];
            r += (du > d) || (du == d && u < v);
        }
        g_perm[li * 1024 + r] = v;
        g_degT[li * 1024 + r] = d;
        g_iperm[li * 1000 + v] = r;
        if ((r & 63) == 0) tmax[r >> 6] = d;
    }
    if (tid < 24) {
        g_perm[li * 1024 + 1000 + tid] = -1;
        g_degT[li * 1024 + 1000 + tid] = 0;
    }
    __syncthreads();
    if (tid == 0) {
        int off = 0;
        for (int t = 0; t < 16; ++t) {
            g_tOff[li * 17 + t] = off;
            off += 64 * tmax[t];
        }
        g_tOff[li * 17 + 16] = off;
    }
}

__global__ void k_scatter()
{
    int i = blockIdx.x * 256 + threadIdx.x;
    if (i >= 3 * 20000) return;
    int li = i / 20000;
    int e = i % 20000;
    int r = e / 20;
    int c = g_tkcol[i];
    if (c < 0) c = 0;
    if (c > 999) c = 999;
    float v = g_tkval[i];
    int pos = g_rp2[li * 1001 + c] + atomicAdd(&g_fill[li * 1000 + c], 1);
    if (pos < 0) pos = 0;
    if (pos > 19999) pos = 19999;
    g_cscr[li * 20000 + pos] = r;
    g_cscv[li * 20000 + pos] = v;
}

// transposed CSR pack: pk1T[li][j][v] = (col*16, w)  (byte-premult for float4)
__global__ void k_packT1()
{
    int i = blockIdx.x * 256 + threadIdx.x;
    if (i >= 60000) return;
    int li = i / 20000;
    int e = i % 20000;
    int v = e / 20, j = e % 20;
    int c1 = g_tkcol[i];
    if (c1 < 0) c1 = 0;
    if (c1 > 999) c1 = 999;
    g_pk1T[li * 20000 + j * 1000 + v] = make_int2(c1 * 16, __float_as_int(g_tkval[i]));
}

// tiled-transposed CSC pack: cscT[tOff[t] + j*64 + lane] = (row*16, w)
__global__ void k_packT2()
{
    int i = blockIdx.x * 256 + threadIdx.x;
    if (i >= 3000) return;
    int li = i / 1000, v = i % 1000;
    int r = g_iperm[li * 1000 + v];
    int t = r >> 6, ln = r & 63;
    int j0 = g_rp2[li * 1001 + v];
    int d = g_rp2[li * 1001 + v + 1] - j0;
    int base = g_tOff[li * 17 + t];
    for (int j = 0; j < d; ++j) {
        int row = g_cscr[li * 20000 + j0 + j];
        if (row < 0) row = 0;
        if (row > 999) row = 999;
        int pos = base + j * 64 + ln;
        if (pos >= 0 && pos < CSCT_CAP)
            g_cscT[li * CSCT_CAP + pos] =
                make_int2(row * 16, __float_as_int(g_cscv[li * 20000 + j0 + j]));
    }
}

// ---------------- pipeline kernels ([n][ch][v] layout, ch = c*L + l) ----------------

__global__ __launch_bounds__(256) void k_skip0(const float* __restrict__ w,
                                               const float* __restrict__ bb)
{
    __shared__ float s_inp[19 * 32];
    __shared__ float s_w[64 * 19];
    int b = blockIdx.y;
    int v0 = blockIdx.x * 32;
    int tid = threadIdx.x;
    for (int i = tid; i < 64 * 19; i += 256) s_w[i] = w[i];
    for (int i = tid; i < 19 * 32; i += 256) {
        int t = i / 32, vl = i % 32;
        int v = v0 + vl;
        s_inp[i] = (v < 1000) ? g_inp[(b * 19 + t) * 1000 + v] : 0.f;
    }
    __syncthreads();
    for (int e = tid; e < 64 * 32; e += 256) {
        int o = e / 32, vl = e % 32;
        int v = v0 + vl;
        if (v >= 1000) continue;
        float acc = bb[o];
#pragma unroll
        for (int t = 0; t < 19; ++t) acc += s_w[o * 19 + t] * s_inp[t * 32 + vl];
        g_skip[(b * 64 + o) * 1000 + v] = acc;
    }
}

// All 4 mixprop hops, one launch, CH_BLK=4 channels per block (float4/col),
// 512-thread blocks: 4 blocks x 8 waves = 32 waves/CU (HW cap) and half
// the per-CU edge-meta traffic vs 256-thread blocks. Per-lane-column
// gathers: CSR via transposed pkT, CSC via degree-sorted ranks + tile-64
// transposed cscT (snake: wave wv takes tiles {wv, 15-wv} per round pair).
// li0: stage sw[c]*g_inp+sb[c] on the fly. Outputs (pure powers):
// o1=P1=MX, o2=P2=M^2X, o3=Q1=M'X, o4=Q2=M'^2X.
__global__ __launch_bounds__(512, 8) void k_prop4(int xsel, int o1s, int o2s, int o3s, int o4s,
                                                  int li, int CH, int li0,
                                                  const float* __restrict__ sw,
                                                  const float* __restrict__ sb)
{
    __shared__ float4 S[2000];   // U = S[0..999], W = S[1000..1999]
    const float* X = bufsel(xsel);
    float* o1 = bufsel(o1s);
    float* o2 = bufsel(o2s);
    float* o3 = bufsel(o3s);
    float* o4 = bufsel(o4s);
    const int2* pkT = g_pk1T + li * 20000;
    const int2* cT = g_cscT + (size_t)li * CSCT_CAP;
    const int* prm = g_perm + li * 1024;
    const int* dgT = g_degT + li * 1024;
    const int* tOf = g_tOff + li * 17;
    const float* iv1 = g_inv1 + li * 1000;
    const float* iv2 = g_inv2 + li * 1000;
    int n = blockIdx.y;
    int ch0 = blockIdx.x * 4;
    size_t gb = ((size_t)n * CH + ch0) * 1000;
    int tid = threadIdx.x;
    int wv = tid >> 6, lane = tid & 63;
    char* Ub = (char*)S;
    char* Wb = (char*)(S + 1000);
    float4* U4 = S;
    float4* W4 = S + 1000;

    // CSR hop: dst[v] = (src[v] + sum_j w_j * src[col_j]) * iv1[v]
    auto csr_hop = [&](const char* sbuf, float4* dst) {
        for (int it = 0; it < 2; ++it) {
            int v = it * 512 + tid;
            if (v >= 1000) break;
            const int2* mp = pkT + v;
            float4 a = *(const float4*)(sbuf + (size_t)v * 16);
#pragma unroll
            for (int jb = 0; jb < 5; ++jb) {
                int2 e0 = mp[(jb * 4 + 0) * 1000];
                int2 e1 = mp[(jb * 4 + 1) * 1000];
                int2 e2 = mp[(jb * 4 + 2) * 1000];
                int2 e3 = mp[(jb * 4 + 3) * 1000];
                float w0 = __int_as_float(e0.y), w1 = __int_as_float(e1.y);
                float w2 = __int_as_float(e2.y), w3 = __int_as_float(e3.y);
                float4 x0 = *(const float4*)(sbuf + e0.x);
                float4 x1 = *(const float4*)(sbuf + e1.x);
                float4 x2 = *(const float4*)(sbuf + e2.x);
                float4 x3 = *(const float4*)(sbuf + e3.x);
                a.x += w0 * x0.x + w1 * x1.x + w2 * x2.x + w3 * x3.x;
                a.y += w0 * x0.y + w1 * x1.y + w2 * x2.y + w3 * x3.y;
                a.z += w0 * x0.z + w1 * x1.z + w2 * x2.z + w3 * x3.z;
                a.w += w0 * x0.w + w1 * x1.w + w2 * x2.w + w3 * x3.w;
            }
            float s = iv1[v];
            a.x *= s; a.y *= s; a.z *= s; a.w *= s;
            dst[v] = a;
        }
    };

    // CSC hop: dst[v] = (src[v] + sum_j w_j * src[row_j]) * iv2[v]
    auto csc_hop = [&](const char* sbuf, float4* dst) {
        for (int o = 0; o < 2; ++o) {
            int tile = o * 8 + ((o & 1) ? (7 - wv) : wv);   // snake balance
            int r = tile * 64 + lane;
            int v = prm[r];
            if (v < 0) continue;
            int d = dgT[r];
            const int2* mp = cT + tOf[tile] + lane;
            float4 a = *(const float4*)(sbuf + (size_t)v * 16);
            int j = 0;
            for (; j + 4 <= d; j += 4) {
                int2 e0 = mp[(j + 0) * 64];
                int2 e1 = mp[(j + 1) * 64];
                int2 e2 = mp[(j + 2) * 64];
                int2 e3 = mp[(j + 3) * 64];
                float w0 = __int_as_float(e0.y), w1 = __int_as_float(e1.y);
                float w2 = __int_as_float(e2.y), w3 = __int_as_float(e3.y);
                float4 x0 = *(const float4*)(sbuf + e0.x);
                float4 x1 = *(const float4*)(sbuf + e1.x);
                float4 x2 = *(const float4*)(sbuf + e2.x);
                float4 x3 = *(const float4*)(sbuf + e3.x);
                a.x += w0 * x0.x + w1 * x1.x + w2 * x2.x + w3 * x3.x;
                a.y += w0 * x0.y + w1 * x1.y + w2 * x2.y + w3 * x3.y;
                a.z += w0 * x0.z + w1 * x1.z + w2 * x2.z + w3 * x3.z;
                a.w += w0 * x0.w + w1 * x1.w + w2 * x2.w + w3 * x3.w;
            }
            for (; j < d; ++j) {
                int2 e = mp[j * 64];
                float w = __int_as_float(e.y);
                float4 x = *(const float4*)(sbuf + e.x);
                a.x += w * x.x; a.y += w * x.y; a.z += w * x.z; a.w += w * x.w;
            }
            float s = iv2[v];
            a.x *= s; a.y *= s; a.z *= s; a.w *= s;
            dst[v] = a;
        }
    };

    // stage X into an LDS buffer (li0: affine of g_inp, else global read)
    auto stage_x = [&](float4* dst) {
        if (li0) {
            float swv0 = sw[(ch0 + 0) / 19], sbv0 = sb[(ch0 + 0) / 19];
            float swv1 = sw[(ch0 + 1) / 19], sbv1 = sb[(ch0 + 1) / 19];
            float swv2 = sw[(ch0 + 2) / 19], sbv2 = sb[(ch0 + 2) / 19];
            float swv3 = sw[(ch0 + 3) / 19], sbv3 = sb[(ch0 + 3) / 19];
            const float* i0 = g_inp + (n * 19 + (ch0 + 0) % 19) * 1000;
            const float* i1 = g_inp + (n * 19 + (ch0 + 1) % 19) * 1000;
            const float* i2 = g_inp + (n * 19 + (ch0 + 2) % 19) * 1000;
            const float* i3 = g_inp + (n * 19 + (ch0 + 3) % 19) * 1000;
            for (int it = 0; it < 2; ++it) {
                int v = it * 512 + tid;
                if (v >= 1000) break;
                float4 t;
                t.x = swv0 * i0[v] + sbv0;
                t.y = swv1 * i1[v] + sbv1;
                t.z = swv2 * i2[v] + sbv2;
                t.w = swv3 * i3[v] + sbv3;
                dst[v] = t;
            }
        } else {
            for (int it = 0; it < 2; ++it) {
                int v = it * 512 + tid;
                if (v >= 1000) break;
                float4 t;
                t.x = X[gb + v];
                t.y = X[gb + 1000 + v];
                t.z = X[gb + 2000 + v];
                t.w = X[gb + 3000 + v];
                dst[v] = t;
            }
        }
    };

    // phase 1: stage X -> U
    stage_x(U4);
    __syncthreads();

    // phase 2: P1 = CSR(U) -> W
    csr_hop(Ub, W4);
    __syncthreads();

    // phase 3: writeback P1; P2 = CSR(W) -> U
    for (int it = 0; it < 2; ++it) {
        int v = it * 512 + tid;
        if (v >= 1000) break;
        float4 t = W4[v];
        o1[gb + v] = t.x;
        o1[gb + 1000 + v] = t.y;
        o1[gb + 2000 + v] = t.z;
        o1[gb + 3000 + v] = t.w;
    }
    csr_hop(Wb, U4);
    __syncthreads();

    // phase 4: writeback P2; restage X -> W (L3/L2-hot)
    for (int it = 0; it < 2; ++it) {
        int v = it * 512 + tid;
        if (v >= 1000) break;
        float4 t = U4[v];
        o2[gb + v] = t.x;
        o2[gb + 1000 + v] = t.y;
        o2[gb + 2000 + v] = t.z;
        o2[gb + 3000 + v] = t.w;
    }
    stage_x(W4);
    __syncthreads();

    // phase 5: Q1 = CSC(W) -> U
    csc_hop(Wb, U4);
    __syncthreads();

    // phase 6: writeback Q1; Q2 = CSC(U) -> W
    for (int it = 0; it < 2; ++it) {
        int v = it * 512 + tid;
        if (v >= 1000) break;
        float4 t = U4[v];
        o3[gb + v] = t.x;
        o3[gb + 1000 + v] = t.y;
        o3[gb + 2000 + v] = t.z;
        o3[gb + 3000 + v] = t.w;
    }
    csc_hop(Ub, W4);
    __syncthreads();

    // phase 7: writeback Q2
    for (int it = 0; it < 2; ++it) {
        int v = it * 512 + tid;
        if (v >= 1000) break;
        float4 t = W4[v];
        o4[gb + v] = t.x;
        o4[gb + 1000 + v] = t.y;
        o4[gb + 2000 + v] = t.z;
        o4[gb + 3000 + v] = t.w;
    }
}

// srcs are {X, P1=Mx, P2=M^2x, Q1=M'x, Q2=M'^2x}; alpha-mix folded into
// the weights (exact): with b=1-a,
//   wx' = wx + a*(w1+w2+w3+w4); wP1 = b*(w1+a*w2); wP2 = b^2*w2;
//   wQ1 = b*(w3+a*w4); wQ2 = b^2*w4.
// li0: X = sw[c]*inp+sb[c] broadcast -> st0 collapses to
//   inp[l][v]*sum_c(wx'[o][c]sw[c]) + sum_c(wx'[o][c]sb[c]).
__global__ __launch_bounds__(256) void k_mix(int xs, int h1s, int h2s, int h3s, int h4s, int ms,
                                             const float* __restrict__ g1w, const float* __restrict__ g2w,
                                             const float* __restrict__ g1b, const float* __restrict__ g2b,
                                             int P, int li0,
                                             const float* __restrict__ sw_,
                                             const float* __restrict__ sb_)
{
    __shared__ float sW[5 * 1024];
    __shared__ float sB[32];
    __shared__ float sWS[32];
    __shared__ float sSB[32];
    int tid = threadIdx.x;
    const float A = ALPHA_C, Bq = 1.f - ALPHA_C;
    for (int i = tid; i < 1024; i += 256) {
        int o = i >> 5, c = i & 31;
        float w1 = g1w[o * 96 + 32 + c], w2 = g1w[o * 96 + 64 + c];
        float w3 = g2w[o * 96 + 32 + c], w4 = g2w[o * 96 + 64 + c];
        sW[i]        = g1w[o * 96 + c] + g2w[o * 96 + c] + A * (w1 + w2 + w3 + w4);
        sW[1024 + i] = Bq * (w1 + A * w2);
        sW[2048 + i] = Bq * Bq * w2;
        sW[3072 + i] = Bq * (w3 + A * w4);
        sW[4096 + i] = Bq * Bq * w4;
    }
    if (tid < 32) sB[tid] = g1b[tid] + g2b[tid];
    __syncthreads();
    if (li0 && tid < 32) {
        float as = 0.f, ab = 0.f;
        for (int c = 0; c < 32; ++c) {
            float w = sW[tid * 32 + c];
            as += w * sw_[c];
            ab += w * sb_[c];
        }
        sWS[tid] = as;
        sSB[tid] = ab;
    }
    if (li0) __syncthreads();
    int n = blockIdx.y;
    int p = blockIdx.x * 256 + tid;
    if (p >= P) return;
    const float* srcs[5] = {bufsel(xs), bufsel(h1s), bufsel(h2s), bufsel(h3s), bufsel(h4s)};
    float acc[32];
    int st0;
    if (li0) {
        float xv = g_inp[(size_t)n * 19000 + p];
#pragma unroll
        for (int o = 0; o < 32; ++o) acc[o] = sB[o] + sSB[o] + sWS[o] * xv;
        st0 = 1;
    } else {
#pragma unroll
        for (int o = 0; o < 32; ++o) acc[o] = sB[o];
        st0 = 0;
    }
    for (int st = st0; st < 5; ++st) {
        const float* src = srcs[st] + (size_t)n * 32 * P + p;
        const float* w = &sW[st * 1024];
        for (int c = 0; c < 32; ++c) {
            float hv = src[(size_t)c * P];
#pragma unroll
            for (int o = 0; o < 32; ++o) acc[o] += w[o * 32 + c] * hv;
        }
    }
    float* XM = bufsel(ms) + (size_t)n * 32 * P + p;
#pragma unroll
    for (int o = 0; o < 32; ++o) XM[(size_t)o * P] = acc[o];
}

// inception + tanh*sigmoid + fused skip-conv (gated values kept in LDS)
template <int LIN>
__global__ __launch_bounds__(256) void k_incept(int xmsel, int xgsel,
                                                const float* __restrict__ fw2, const float* __restrict__ fw3,
                                                const float* __restrict__ fw6, const float* __restrict__ fw7,
                                                const float* __restrict__ fb,
                                                const float* __restrict__ gw2, const float* __restrict__ gw3,
                                                const float* __restrict__ gw6, const float* __restrict__ gw7,
                                                const float* __restrict__ gb,
                                                const float* __restrict__ skw, const float* __restrict__ skb)
{
    const int LOUT = LIN - 6;
    const float* XM = bufsel(xmsel);
    float* XG = bufsel(xgsel);
    __shared__ float sx[32 * 8 * LIN];
    __shared__ float sxg[32 * 8 * LOUT];
    int tid = threadIdx.x;
    int n = blockIdx.y, v0 = blockIdx.x * 8;
    for (int i = tid; i < 32 * LIN * 8; i += 256) {
        int vl = i & 7;
        int l = (i >> 3) % LIN;
        int c = i / (8 * LIN);
        sx[(c * 8 + vl) * LIN + l] = XM[(((size_t)n * 32 + c) * LIN + l) * 1000 + v0 + vl];
    }
    __syncthreads();
    int co = tid >> 3, vl = tid & 7;
    int s = co >> 3, co_s = co & 7;
    const int ksz[4] = {2, 3, 6, 7};
    int k = ksz[s];
    const float* fw = (s == 0) ? fw2 : ((s == 1) ? fw3 : ((s == 2) ? fw6 : fw7));
    const float* gw = (s == 0) ? gw2 : ((s == 1) ? gw3 : ((s == 2) ? gw6 : gw7));
    float accf[LOUT], accg[LOUT];
    float bf = fb[co], bg = gb[co];
#pragma unroll
    for (int l = 0; l < LOUT; ++l) { accf[l] = bf; accg[l] = bg; }
    for (int c = 0; c < 32; ++c) {
        const float* xp = &sx[(c * 8 + vl) * LIN];
        for (int j = 0; j < k; ++j) {
            float wf = fw[(co_s * 32 + c) * k + j];
            float wg = gw[(co_s * 32 + c) * k + j];
            int base = 7 - k + j;
#pragma unroll
            for (int l = 0; l < LOUT; ++l) {
                float xv = xp[base + l];
                accf[l] += wf * xv;
                accg[l] += wg * xv;
            }
        }
    }
    size_t ob = ((size_t)n * 32 + co) * LOUT * 1000 + v0 + vl;
#pragma unroll
    for (int l = 0; l < LOUT; ++l) {
        float g = tanhf(accf[l]) * (1.f / (1.f + expf(-accg[l])));
        XG[ob + (size_t)l * 1000] = g;
        sxg[(co * 8 + vl) * LOUT + l] = g;
    }
    __syncthreads();
    int obk = tid >> 3;
    for (int half = 0; half < 2; ++half) {
        int o = obk + 32 * half;
        float acc = skb[o];
        for (int c = 0; c < 32; ++c) {
            const float* wp = &skw[((size_t)o * 32 + c) * LOUT];
            const float* xp = &sxg[(c * 8 + vl) * LOUT];
#pragma unroll
            for (int l = 0; l < LOUT; ++l) acc += wp[l] * xp[l];
        }
        size_t si = ((size_t)n * 64 + o) * 1000 + v0 + vl;
        g_skip[si] += acc;
    }
}

__global__ __launch_bounds__(256) void k_resid_stats(int xnsel, int xpsel,
                                                     int li, int LIN, int LOUT, int li0,
                                                     const float* __restrict__ sw_,
                                                     const float* __restrict__ sb_)
{
    float* XN = bufsel(xnsel);
    const float* Xp = bufsel(xpsel);
    float* stats = g_stats + li * 64;
    int n = blockIdx.y;
    int S = 32 * LOUT * 1000;
    int tid = threadIdx.x;
    int gsz = gridDim.x * 256;
    float sum = 0.f, ss = 0.f;
    for (int idx = blockIdx.x * 256 + tid; idx < S; idx += gsz) {
        int v = idx % 1000;
        int l = (idx / 1000) % LOUT;
        int c = idx / (1000 * LOUT);
        float r;
        if (li0)
            r = sw_[c] * g_inp[(n * 19 + l + 6) * 1000 + v] + sb_[c];
        else
            r = Xp[(((size_t)n * 32 + c) * LIN + l + (LIN - LOUT)) * 1000 + v];
        float y = XN[(size_t)n * S + idx] + r;
        XN[(size_t)n * S + idx] = y;
        sum += y;
        ss += y * y;
    }
    __shared__ float s1[256], s2[256];
    s1[tid] = sum;
    s2[tid] = ss;
    __syncthreads();
    for (int s = 128; s > 0; s >>= 1) {
        if (tid < s) { s1[tid] += s1[tid + s]; s2[tid] += s2[tid + s]; }
        __syncthreads();
    }
    if (tid == 0) {
        atomicAdd(&stats[n * 2], s1[0]);
        atomicAdd(&stats[n * 2 + 1], s2[0]);
    }
}

__global__ void k_norm(int xnsel, const float* __restrict__ nw,
                       const float* __restrict__ nb, int li, int LOUT)
{
    float* XN = bufsel(xnsel);
    const float* stats = g_stats + li * 64;
    int S = 32 * LOUT * 1000;
    long long total = (long long)NBC * S;
    long long stride = (long long)gridDim.x * 256;
    for (long long i = (long long)blockIdx.x * 256 + threadIdx.x; i < total; i += stride) {
        int n = (int)(i / S);
        int rem = (int)(i % S);
        int v = rem % 1000;
        int l = (rem / 1000) % LOUT;
        int c = rem / (1000 * LOUT);
        int widx = (c * 1000 + v) * LOUT + l;
        float cnt = (float)S;
        float mu = stats[n * 2] / cnt;
        float var = stats[n * 2 + 1] / cnt - mu * mu;
        float rs = rsqrtf(var + EPS_C);
        XN[i] = (XN[i] - mu) * rs * nw[widx] + nb[widx];
    }
}

__global__ __launch_bounds__(256) void k_final(int xsel,
                                               const float* __restrict__ ew, const float* __restrict__ eb,
                                               const float* __restrict__ e1w, const float* __restrict__ e1b,
                                               const float* __restrict__ e2w, const float* __restrict__ e2b,
                                               float* __restrict__ out)
{
    const float* X = bufsel(xsel);
    __shared__ float sxf[32 * 16];
    __shared__ float sk[64 * 16];
    __shared__ float s1[64 * 16];
    __shared__ float s2[128 * 16];
    int b = blockIdx.y, v0 = blockIdx.x * 16;
    int tid = threadIdx.x;
    for (int i = tid; i < 512; i += 256) {
        int c = i / 16, vl = i & 15;
        int v = v0 + vl;
        sxf[i] = (v < 1000) ? X[((size_t)b * 32 + c) * 1000 + v] : 0.f;
    }
    for (int i = tid; i < 1024; i += 256) {
        int o = i / 16, vl = i & 15;
        int v = v0 + vl;
        sk[i] = (v < 1000) ? g_skip[((size_t)b * 64 + o) * 1000 + v] : 0.f;
    }
    __syncthreads();
    for (int i = tid; i < 1024; i += 256) {
        int o = i / 16, vl = i & 15;
        float acc = sk[i] + eb[o];
        for (int c = 0; c < 32; ++c) acc += ew[o * 32 + c] * sxf[c * 16 + vl];
        s1[i] = fmaxf(acc, 0.f);
    }
    __syncthreads();
    for (int i = tid; i < 2048; i += 256) {
        int o = i / 16, vl = i & 15;
        float acc = e1b[o];
        for (int c = 0; c < 64; ++c) acc += e1w[o * 64 + c] * s1[c * 16 + vl];
        s2[i] = fmaxf(acc, 0.f);
    }
    __syncthreads();
    if (tid < 192) {
        int o = tid / 16, vl = tid & 15;
        int v = v0 + vl;
        if (v < 1000) {
            float acc = e2b[o];
            for (int c = 0; c < 128; ++c) acc += e2w[o * 128 + c] * s2[c * 16 + vl];
            out[((size_t)b * 12 + o) * 1000 + v] = acc;
        }
    }
}

// ---------------- host ----------------

static const int SZ_SORT[43] = {240000,240000,128,8192,12,1536,96,1536,2304,4608,
                                5376,96,9216,96,9216,96,1536,2304,4608,5376,
                                480,19200,480,19200,416000,224000,32000,416000,224000,32000,
                                64,1216,64,2048,64,64,64,26624,14336,2048,32,32,768000};
static const int SZ_DICT[43] = {768000,32,32,1216,64,240000,240000,19200,480,19200,
                                480,9216,96,9216,96,1536,2304,4608,5376,96,
                                1536,2304,4608,5376,96,26624,64,416000,416000,14336,
                                64,224000,224000,2048,64,32000,32000,2048,64,8192,128,1536,12};
static const int SZ_SIG[43]  = {768000,32,32,1216,64,240000,240000,19200,480,19200,
                                480,9216,96,9216,96,1536,2304,4608,5376,96,
                                1536,2304,4608,5376,96,26624,64,14336,64,2048,
                                64,416000,416000,224000,224000,32000,32000,2048,64,8192,128,1536,12};

extern "C" void kernel_launch(void* const* d_in, const int* in_sizes, int n_in,
                              void* d_out, int out_size, void* d_ws, size_t ws_size,
                              hipStream_t stream)
{
    (void)d_ws; (void)ws_size;
    const float *x_in, *start_w, *start_b, *skip0_w, *skip0_b;
    const float *emb1, *emb2, *lin1_w, *lin1_b, *lin2_w, *lin2_b;
    const float *g1_w, *g1_b, *g2_w, *g2_b;
    const float *filt_w[4], *filt_b, *gate_w[4], *gate_b;
    const float *skw[3], *skb[3], *nww[3], *nbb[3];
    const float *skipE_w, *skipE_b, *end1_w, *end1_b, *end2_w, *end2_b;
    float* outp = (float*)d_out;
    auto P = [&](int i) { return (const float*)d_in[i]; };
    auto match = [&](const int* tab) {
        if (n_in < 43) return false;
        for (int i = 0; i < 43; ++i) if (in_sizes[i] != tab[i]) return false;
        return true;
    };

    int fam = -1;
    if (match(SZ_SORT)) fam = 0;
    else if (match(SZ_DICT)) fam = 1;
    else if (match(SZ_SIG)) fam = 2;

    if (fam == 0) {
        emb1 = P(0); emb2 = P(1); end1_b = P(2); end1_w = P(3); end2_b = P(4); end2_w = P(5);
        filt_b = P(6); filt_w[0] = P(7); filt_w[1] = P(8); filt_w[2] = P(9); filt_w[3] = P(10);
        g1_b = P(11); g1_w = P(12); g2_b = P(13); g2_w = P(14);
        gate_b = P(15); gate_w[0] = P(16); gate_w[1] = P(17); gate_w[2] = P(18); gate_w[3] = P(19);
        lin1_b = P(20); lin1_w = P(21); lin2_b = P(22); lin2_w = P(23);
        nbb[0] = P(24); nbb[1] = P(25); nbb[2] = P(26);
        nww[0] = P(27); nww[1] = P(28); nww[2] = P(29);
        skip0_b = P(30); skip0_w = P(31); skipE_b = P(32); skipE_w = P(33);
        skb[0] = P(34); skb[1] = P(35); skb[2] = P(36);
        skw[0] = P(37); skw[1] = P(38); skw[2] = P(39);
        start_b = P(40); start_w = P(41); x_in = P(42);
    } else if (fam == 1 || fam == 2) {
        x_in = P(0); start_w = P(1); start_b = P(2); skip0_w = P(3); skip0_b = P(4);
        emb1 = P(5); emb2 = P(6); lin1_w = P(7); lin1_b = P(8); lin2_w = P(9); lin2_b = P(10);
        g1_w = P(11); g1_b = P(12); g2_w = P(13); g2_b = P(14);
        filt_w[0] = P(15); filt_w[1] = P(16); filt_w[2] = P(17); filt_w[3] = P(18); filt_b = P(19);
        gate_w[0] = P(20); gate_w[1] = P(21); gate_w[2] = P(22); gate_w[3] = P(23); gate_b = P(24);
        if (fam == 1) {
            skw[0] = P(25); skb[0] = P(26); nww[0] = P(27); nbb[0] = P(28);
            skw[1] = P(29); skb[1] = P(30); nww[1] = P(31); nbb[1] = P(32);
            skw[2] = P(33); skb[2] = P(34); nww[2] = P(35); nbb[2] = P(36);
        } else {
            skw[0] = P(25); skb[0] = P(26); skw[1] = P(27); skb[1] = P(28);
            skw[2] = P(29); skb[2] = P(30);
            nww[0] = P(31); nbb[0] = P(32); nww[1] = P(33); nbb[1] = P(34);
            nww[2] = P(35); nbb[2] = P(36);
        }
        skipE_w = P(37); skipE_b = P(38); end1_w = P(39); end1_b = P(40);
        end2_w = P(41); end2_b = P(42);
    } else {
        k_out_zero<<<(out_size + 255) / 256, 256, 0, stream>>>(outp, out_size);
        k_marker<<<1, 64, 0, stream>>>(outp, 8192.0f);
        return;
    }

    // ---- setup ----
    k_init<<<12, 256, 0, stream>>>();
    k_build_inp<<<(32 * 19 * 1000 + 255) / 256, 256, 0, stream>>>(x_in);
    k_nv<<<(240000 + 255) / 256, 256, 0, stream>>>(emb1, emb2, lin1_w, lin1_b, lin2_w, lin2_b);
    k_adj_topk<<<3000, 256, 0, stream>>>();
    k_scan<<<3, 256, 0, stream>>>();
    k_permsort<<<3, 256, 0, stream>>>();
    k_scatter<<<(60000 + 255) / 256, 256, 0, stream>>>();
    k_packT1<<<(60000 + 255) / 256, 256, 0, stream>>>();
    k_packT2<<<12, 256, 0, stream>>>();

    // ---- full-batch pipeline (k_start folded into prop4/mix/resid li0) ----
    k_skip0<<<dim3(32, NBC), 256, 0, stream>>>(skip0_w, skip0_b);

    int X = 0;   // layer-0 "X buffer" is virtual (affine of g_inp)
    int LIN = 19;
    for (int li = 0; li < 3; ++li) {
        int LOUT = LIN - 6;
        int Pp = 1000 * LIN;
        int li0 = (li == 0) ? 1 : 0;
        int hb[4], hn = 0;
        for (int b = 0; b < 6 && hn < 4; ++b)
            if (b != X && b != 1) hb[hn++] = b;
        int h1 = hb[0], h2 = hb[1], h3 = hb[2], h4 = hb[3];
        int CH = 32 * LIN;
        dim3 gg((unsigned)(CH / 4), NBC);

        // all 4 hops in one launch: o1=P1, o2=P2, o3=Q1, o4=Q2
        k_prop4<<<gg, 512, 0, stream>>>(X, h1, h2, h3, h4, li, CH, li0, start_w, start_b);

        k_mix<<<dim3((Pp + 255) / 256, NBC), 256, 0, stream>>>(X, h1, h2, h3, h4, 1,
            g1_w + li * 3072, g2_w + li * 3072, g1_b + li * 32, g2_b + li * 32, Pp,
            li0, start_w, start_b);

        int XG = h1;
        if (LIN == 19)
            k_incept<19><<<dim3(125, NBC), 256, 0, stream>>>(1, XG,
                filt_w[0] + li * 512, filt_w[1] + li * 768, filt_w[2] + li * 1536, filt_w[3] + li * 1792,
                filt_b + li * 32,
                gate_w[0] + li * 512, gate_w[1] + li * 768, gate_w[2] + li * 1536, gate_w[3] + li * 1792,
                gate_b + li * 32, skw[li], skb[li]);
        else if (LIN == 13)
            k_incept<13><<<dim3(125, NBC), 256, 0, stream>>>(1, XG,
                filt_w[0] + li * 512, filt_w[1] + li * 768, filt_w[2] + li * 1536, filt_w[3] + li * 1792,
                filt_b + li * 32,
                gate_w[0] + li * 512, gate_w[1] + li * 768, gate_w[2] + li * 1536, gate_w[3] + li * 1792,
                gate_b + li * 32, skw[li], skb[li]);
        else
            k_incept<7><<<dim3(125, NBC), 256, 0, stream>>>(1, XG,
                filt_w[0] + li * 512, filt_w[1] + li * 768, filt_w[2] + li * 1536, filt_w[3] + li * 1792,
                filt_b + li * 32,
                gate_w[0] + li * 512, gate_w[1] + li * 768, gate_w[2] + li * 1536, gate_w[3] + li * 1792,
                gate_b + li * 32, skw[li], skb[li]);

        k_resid_stats<<<dim3(16, NBC), 256, 0, stream>>>(XG, X, li, LIN, LOUT,
                                                         li0, start_w, start_b);
        k_norm<<<2048, 256, 0, stream>>>(XG, nww[li], nbb[li], li, LOUT);

        X = XG;
        LIN = LOUT;
    }
    k_final<<<dim3(63, NBC), 256, 0, stream>>>(X, skipE_w, skipE_b,
                                               end1_w, end1_b, end2_w, end2_b, outp);
}

// Round 9
// 2670.955 us; speedup vs baseline: 1.0244x; 1.0244x over previous
//
#include <hip/hip_runtime.h>
#include <math.h>

// CoGNN forward. Round 38 (best = r36 2654us; r37 2736 REGRESSION).
// r37 A/B established: VGPR/ILP > occupancy for prop4 (512thr forced
// VGPR 48->32, dur 422->466 despite Occ 55->89%). Revert prop4 to r36's
// exact 256-thread/bounds(256,5)/48-VGPR config. Keep k_norm grid-stride.
// NEW: float4-ize the 40-elem dot products in k_adj_topk and k_nv
// (bases 160B-aligned; sequential component adds = bit-identical FP).
// Everything else = r36 (li0 folding, shfl topk, per-lane float4 gathers,
// pure powers P1,P2,Q1,Q2, alpha folded into k_mix).
// B=32,C=32,V=1000,L:19->13->7->1. fp32.

#define ALPHA_C 0.05f
#define EPS_C 1e-5f
#define NBC 32
#define CSCT_CAP 140000

// ---------------- static device workspace ----------------
__device__ float g_inp[32 * 19 * 1000];
__device__ float g_skip[32 * 64 * 1000];
__device__ __align__(16) float g_nv1[240000];
__device__ __align__(16) float g_nv2[240000];
__device__ __align__(16) int   g_tkcol[60000];
__device__ __align__(16) float g_tkval[60000];
__device__ float g_inv1[3000];
__device__ int   g_colcnt[3000];
__device__ float g_colsum[3000];
__device__ int   g_rp2[3 * 1001 + 1];
__device__ int   g_fill[3000];
__device__ int   g_cscr[60000];
__device__ float g_cscv[60000];
__device__ float g_inv2[3000];
__device__ float g_stats[3 * 64];
__device__ __align__(16) int2 g_pk1T[60000];        // CSR transposed [li][j][v] = (col*16, w)
__device__ __align__(16) int2 g_cscT[3 * CSCT_CAP]; // CSC tiled-transposed (row*16, w)
__device__ int   g_perm[3 * 1024];   // [li][rank] -> v (global degree desc; -1 sentinel)
__device__ int   g_degT[3 * 1024];   // [li][rank] -> degree
__device__ int   g_iperm[3 * 1000];  // [li][v] -> rank
__device__ int   g_tOff[3 * 17];     // [li][tile] -> cscT base offset
__device__ float g_B0[(size_t)NBC * 32 * 19 * 1000];
__device__ float g_B1[(size_t)NBC * 32 * 19 * 1000];
__device__ float g_B2[(size_t)NBC * 32 * 19 * 1000];
__device__ float g_B3[(size_t)NBC * 32 * 19 * 1000];
__device__ float g_B4[(size_t)NBC * 32 * 19 * 1000];
__device__ float g_B5[(size_t)NBC * 32 * 19 * 1000];

__device__ __forceinline__ float* bufsel(int s)
{
    switch (s) {
        case 0: return g_B0;
        case 1: return g_B1;
        case 2: return g_B2;
        case 3: return g_B3;
        case 4: return g_B4;
        default: return g_B5;
    }
}

__global__ void k_init()
{
    int i = blockIdx.x * 256 + threadIdx.x;
    if (i < 3000) { g_colcnt[i] = 0; g_colsum[i] = 0.f; g_fill[i] = 0; }
    if (i < 192) g_stats[i] = 0.f;
}

__global__ void k_out_zero(float* __restrict__ out, int n)
{
    int i = blockIdx.x * 256 + threadIdx.x;
    if (i < n) out[i] = 0.0f;
}

__global__ void k_marker(float* __restrict__ out, float v)
{
    if (threadIdx.x == 0) out[0] = v;
}

// ---------------- setup ----------------

__global__ void k_build_inp(const float* __restrict__ xin)
{
    int i = blockIdx.x * 256 + threadIdx.x;
    if (i >= 32 * 19 * 1000) return;
    int v = i % 1000;
    int t = (i / 1000) % 19;
    int b = i / 19000;
    float val = 0.f;
    if (t >= 7) {
        int tt = t - 7;
        int n = (v < 500) ? v : v - 500;
        int f = (v < 500) ? 0 : 1;
        val = xin[((b * 12 + tt) * 500 + n) * 4 + f];
    }
    g_inp[i] = val;
}

__global__ void k_nv(const float* __restrict__ e1, const float* __restrict__ e2,
                     const float* __restrict__ w1, const float* __restrict__ b1,
                     const float* __restrict__ w2, const float* __restrict__ b2)
{
    int i = blockIdx.x * 256 + threadIdx.x;
    if (i >= 12 * 500 * 40) return;
    int o = i % 40;
    int n = (i / 40) % 500;
    int m = i / (40 * 500);
    const float4* p1 = (const float4*)(e1 + (m * 500 + n) * 40);
    const float4* pw1 = (const float4*)(w1 + (m * 40 + o) * 40);
    const float4* p2 = (const float4*)(e2 + (m * 500 + n) * 40);
    const float4* pw2 = (const float4*)(w2 + (m * 40 + o) * 40);
    float a1 = b1[m * 40 + o], a2 = b2[m * 40 + o];
    for (int d = 0; d < 10; ++d) {
        float4 x1 = p1[d], y1 = pw1[d];
        float4 x2 = p2[d], y2 = pw2[d];
        a1 += x1.x * y1.x; a1 += x1.y * y1.y; a1 += x1.z * y1.z; a1 += x1.w * y1.w;
        a2 += x2.x * y2.x; a2 += x2.y * y2.y; a2 += x2.z * y2.z; a2 += x2.w * y2.w;
    }
    g_nv1[i] = a1;
    g_nv2[i] = a2;
}

__global__ __launch_bounds__(256) void k_adj_topk()
{
    __shared__ float row[1000];
    __shared__ float wvv[4];
    __shared__ int wvi[4];
    __shared__ int selc[20];
    __shared__ float selv[20];
    int li = blockIdx.x / 1000;
    int r = blockIdx.x % 1000;
    int tid = threadIdx.x;
    int wv = tid >> 6, lane = tid & 63;
    int bi = r / 500, n = r % 500;
    for (int c = tid; c < 1000; c += 256) {
        int bj = c / 500, k = c % 500;
        int mg = li * 4 + 2 * bi + bj;
        const float4* a = (const float4*)(g_nv1 + (mg * 500 + n) * 40);
        const float4* b = (const float4*)(g_nv2 + (mg * 500 + k) * 40);
        float acc = 0.f;
#pragma unroll
        for (int d = 0; d < 10; ++d) {
            float4 av = a[d], bv = b[d];
            acc += av.x * bv.x; acc += av.y * bv.y;
            acc += av.z * bv.z; acc += av.w * bv.w;
        }
        row[c] = acc;
    }
    __syncthreads();
    for (int sel = 0; sel < 20; ++sel) {
        float bv = -INFINITY;
        int bidx = 0;
        for (int c = tid; c < 1000; c += 256) {
            float x = row[c];
            if (x > bv) { bv = x; bidx = c; }
        }
#pragma unroll
        for (int m = 1; m < 64; m <<= 1) {
            float ov = __shfl_xor(bv, m);
            int oi = __shfl_xor(bidx, m);
            if (ov > bv || (ov == bv && oi < bidx)) { bv = ov; bidx = oi; }
        }
        if (lane == 0) { wvv[wv] = bv; wvi[wv] = bidx; }
        __syncthreads();
        if (tid == 0) {
            float fv = wvv[0];
            int fi = wvi[0];
#pragma unroll
            for (int k = 1; k < 4; ++k) {
                float ov = wvv[k];
                int oi = wvi[k];
                if (ov > fv || (ov == fv && oi < fi)) { fv = ov; fi = oi; }
            }
            int ci = fi;
            if (ci < 0 || ci > 999) ci = sel;
            selc[sel] = ci;
            selv[sel] = fv;
            g_tkcol[(li * 1000 + r) * 20 + sel] = ci;
            g_tkval[(li * 1000 + r) * 20 + sel] = fv;
            row[ci] = -INFINITY;
        }
        __syncthreads();
    }
    if (tid < 20) {
        atomicAdd(&g_colcnt[li * 1000 + selc[tid]], 1);
        atomicAdd(&g_colsum[li * 1000 + selc[tid]], selv[tid]);
    }
    if (tid == 0) {
        float s = 0.f;
        for (int j = 0; j < 20; ++j) s += selv[j];
        g_inv1[li * 1000 + r] = 1.f / (s + 1.f);
    }
}

__global__ __launch_bounds__(256) void k_scan()
{
    __shared__ int s[1000];
    int li = blockIdx.x;
    int tid = threadIdx.x;
    for (int i = tid; i < 1000; i += 256) s[i] = g_colcnt[li * 1000 + i];
    __syncthreads();
    if (tid == 0) {
        int run = 0;
        for (int i = 0; i < 1000; ++i) { int c = s[i]; s[i] = run; run += c; }
        g_rp2[li * 1001 + 1000] = run;
    }
    __syncthreads();
    for (int i = tid; i < 1000; i += 256) {
        g_rp2[li * 1001 + i] = s[i];
        g_inv2[li * 1000 + i] = 1.f / (g_colsum[li * 1000 + i] + 1.f);
    }
}

// global exact degree rank sort (desc, ties by index) + tile offsets
__global__ __launch_bounds__(256) void k_permsort()
{
    __shared__ int deg[1000];
    __shared__ int tmax[16];
    int li = blockIdx.x;
    int tid = threadIdx.x;
    for (int v = tid; v < 1000; v += 256)
        deg[v] = g_rp2[li * 1001 + v + 1] - g_rp2[li * 1001 + v];
    __syncthreads();
    for (int v = tid; v < 1000; v += 256) {
        int d = deg[v];
        int r = 0;
        for (int u = 0; u < 1000; ++u) {
            int du = deg[u];
            r += (du > d) || (du == d && u < v);
        }
        g_perm[li * 1024 + r] = v;
        g_degT[li * 1024 + r] = d;
        g_iperm[li * 1000 + v] = r;
        if ((r & 63) == 0) tmax[r >> 6] = d;
    }
    if (tid < 24) {
        g_perm[li * 1024 + 1000 + tid] = -1;
        g_degT[li * 1024 + 1000 + tid] = 0;
    }
    __syncthreads();
    if (tid == 0) {
        int off = 0;
        for (int t = 0; t < 16; ++t) {
            g_tOff[li * 17 + t] = off;
            off += 64 * tmax[t];
        }
        g_tOff[li * 17 + 16] = off;
    }
}

__global__ void k_scatter()
{
    int i = blockIdx.x * 256 + threadIdx.x;
    if (i >= 3 * 20000) return;
    int li = i / 20000;
    int e = i % 20000;
    int r = e / 20;
    int c = g_tkcol[i];
    if (c < 0) c = 0;
    if (c > 999) c = 999;
    float v = g_tkval[i];
    int pos = g_rp2[li * 1001 + c] + atomicAdd(&g_fill[li * 1000 + c], 1);
    if (pos < 0) pos = 0;
    if (pos > 19999) pos = 19999;
    g_cscr[li * 20000 + pos] = r;
    g_cscv[li * 20000 + pos] = v;
}

// transposed CSR pack: pk1T[li][j][v] = (col*16, w)  (byte-premult for float4)
__global__ void k_packT1()
{
    int i = blockIdx.x * 256 + threadIdx.x;
    if (i >= 60000) return;
    int li = i / 20000;
    int e = i % 20000;
    int v = e / 20, j = e % 20;
    int c1 = g_tkcol[i];
    if (c1 < 0) c1 = 0;
    if (c1 > 999) c1 = 999;
    g_pk1T[li * 20000 + j * 1000 + v] = make_int2(c1 * 16, __float_as_int(g_tkval[i]));
}

// tiled-transposed CSC pack: cscT[tOff[t] + j*64 + lane] = (row*16, w)
__global__ void k_packT2()
{
    int i = blockIdx.x * 256 + threadIdx.x;
    if (i >= 3000) return;
    int li = i / 1000, v = i % 1000;
    int r = g_iperm[li * 1000 + v];
    int t = r >> 6, ln = r & 63;
    int j0 = g_rp2[li * 1001 + v];
    int d = g_rp2[li * 1001 + v + 1] - j0;
    int base = g_tOff[li * 17 + t];
    for (int j = 0; j < d; ++j) {
        int row = g_cscr[li * 20000 + j0 + j];
        if (row < 0) row = 0;
        if (row > 999) row = 999;
        int pos = base + j * 64 + ln;
        if (pos >= 0 && pos < CSCT_CAP)
            g_cscT[li * CSCT_CAP + pos] =
                make_int2(row * 16, __float_as_int(g_cscv[li * 20000 + j0 + j]));
    }
}

// ---------------- pipeline kernels ([n][ch][v] layout, ch = c*L + l) ----------------

__global__ __launch_bounds__(256) void k_skip0(const float* __restrict__ w,
                                               const float* __restrict__ bb)
{
    __shared__ float s_inp[19 * 32];
    __shared__ float s_w[64 * 19];
    int b = blockIdx.y;
    int v0 = blockIdx.x * 32;
    int tid = threadIdx.x;
    for (int i = tid; i < 64 * 19; i += 256) s_w[i] = w[i];
    for (int i = tid; i < 19 * 32; i += 256) {
        int t = i / 32, vl = i % 32;
        int v = v0 + vl;
        s_inp[i] = (v < 1000) ? g_inp[(b * 19 + t) * 1000 + v] : 0.f;
    }
    __syncthreads();
    for (int e = tid; e < 64 * 32; e += 256) {
        int o = e / 32, vl = e % 32;
        int v = v0 + vl;
        if (v >= 1000) continue;
        float acc = bb[o];
#pragma unroll
        for (int t = 0; t < 19; ++t) acc += s_w[o * 19 + t] * s_inp[t * 32 + vl];
        g_skip[(b * 64 + o) * 1000 + v] = acc;
    }
}

// All 4 mixprop hops, one launch, CH_BLK=4 channels per block (float4/col).
// Per-lane-column gathers (r34/r36-proven): CSR via transposed pkT, CSC via
// degree-sorted ranks + tile-64 transposed cscT, snake tile assignment.
// Indices byte-premultiplied (col*16). li0: stage sw[c]*g_inp+sb[c] on the
// fly. 256 threads, bounds (256,5): 48-VGPR codegen + 20 waves/CU (r37 A/B:
// ILP beats occupancy here). Outputs: o1=P1, o2=P2, o3=Q1, o4=Q2.
__global__ __launch_bounds__(256, 5) void k_prop4(int xsel, int o1s, int o2s, int o3s, int o4s,
                                                  int li, int CH, int li0,
                                                  const float* __restrict__ sw,
                                                  const float* __restrict__ sb)
{
    __shared__ float4 S[2000];   // U = S[0..999], W = S[1000..1999]
    const float* X = bufsel(xsel);
    float* o1 = bufsel(o1s);
    float* o2 = bufsel(o2s);
    float* o3 = bufsel(o3s);
    float* o4 = bufsel(o4s);
    const int2* pkT = g_pk1T + li * 20000;
    const int2* cT = g_cscT + (size_t)li * CSCT_CAP;
    const int* prm = g_perm + li * 1024;
    const int* dgT = g_degT + li * 1024;
    const int* tOf = g_tOff + li * 17;
    const float* iv1 = g_inv1 + li * 1000;
    const float* iv2 = g_inv2 + li * 1000;
    int n = blockIdx.y;
    int ch0 = blockIdx.x * 4;
    size_t gb = ((size_t)n * CH + ch0) * 1000;
    int tid = threadIdx.x;
    int wv = tid >> 6, lane = tid & 63;
    char* Ub = (char*)S;
    char* Wb = (char*)(S + 1000);
    float4* U4 = S;
    float4* W4 = S + 1000;

    // CSR hop: dst[v] = (src[v] + sum_j w_j * src[col_j]) * iv1[v]
    auto csr_hop = [&](const char* sbuf, float4* dst) {
        for (int it = 0; it < 4; ++it) {
            int v = it * 256 + tid;
            if (v >= 1000) break;
            const int2* mp = pkT + v;
            float4 a = *(const float4*)(sbuf + (size_t)v * 16);
#pragma unroll
            for (int jb = 0; jb < 5; ++jb) {
                int2 e0 = mp[(jb * 4 + 0) * 1000];
                int2 e1 = mp[(jb * 4 + 1) * 1000];
                int2 e2 = mp[(jb * 4 + 2) * 1000];
                int2 e3 = mp[(jb * 4 + 3) * 1000];
                float w0 = __int_as_float(e0.y), w1 = __int_as_float(e1.y);
                float w2 = __int_as_float(e2.y), w3 = __int_as_float(e3.y);
                float4 x0 = *(const float4*)(sbuf + e0.x);
                float4 x1 = *(const float4*)(sbuf + e1.x);
                float4 x2 = *(const float4*)(sbuf + e2.x);
                float4 x3 = *(const float4*)(sbuf + e3.x);
                a.x += w0 * x0.x + w1 * x1.x + w2 * x2.x + w3 * x3.x;
                a.y += w0 * x0.y + w1 * x1.y + w2 * x2.y + w3 * x3.y;
                a.z += w0 * x0.z + w1 * x1.z + w2 * x2.z + w3 * x3.z;
                a.w += w0 * x0.w + w1 * x1.w + w2 * x2.w + w3 * x3.w;
            }
            float s = iv1[v];
            a.x *= s; a.y *= s; a.z *= s; a.w *= s;
            dst[v] = a;
        }
    };

    // CSC hop: dst[v] = (src[v] + sum_j w_j * src[row_j]) * iv2[v]
    auto csc_hop = [&](const char* sbuf, float4* dst) {
        for (int o = 0; o < 4; ++o) {
            int tile = o * 4 + ((o & 1) ? (3 - wv) : wv);   // snake balance
            int r = tile * 64 + lane;
            int v = prm[r];
            if (v < 0) continue;
            int d = dgT[r];
            const int2* mp = cT + tOf[tile] + lane;
            float4 a = *(const float4*)(sbuf + (size_t)v * 16);
            int j = 0;
            for (; j + 4 <= d; j += 4) {
                int2 e0 = mp[(j + 0) * 64];
                int2 e1 = mp[(j + 1) * 64];
                int2 e2 = mp[(j + 2) * 64];
                int2 e3 = mp[(j + 3) * 64];
                float w0 = __int_as_float(e0.y), w1 = __int_as_float(e1.y);
                float w2 = __int_as_float(e2.y), w3 = __int_as_float(e3.y);
                float4 x0 = *(const float4*)(sbuf + e0.x);
                float4 x1 = *(const float4*)(sbuf + e1.x);
                float4 x2 = *(const float4*)(sbuf + e2.x);
                float4 x3 = *(const float4*)(sbuf + e3.x);
                a.x += w0 * x0.x + w1 * x1.x + w2 * x2.x + w3 * x3.x;
                a.y += w0 * x0.y + w1 * x1.y + w2 * x2.y + w3 * x3.y;
                a.z += w0 * x0.z + w1 * x1.z + w2 * x2.z + w3 * x3.z;
                a.w += w0 * x0.w + w1 * x1.w + w2 * x2.w + w3 * x3.w;
            }
            for (; j < d; ++j) {
                int2 e = mp[j * 64];
                float w = __int_as_float(e.y);
                float4 x = *(const float4*)(sbuf + e.x);
                a.x += w * x.x; a.y += w * x.y; a.z += w * x.z; a.w += w * x.w;
            }
            float s = iv2[v];
            a.x *= s; a.y *= s; a.z *= s; a.w *= s;
            dst[v] = a;
        }
    };

    // stage X into an LDS buffer (li0: affine of g_inp, else global read)
    auto stage_x = [&](float4* dst) {
        if (li0) {
            float swv0 = sw[(ch0 + 0) / 19], sbv0 = sb[(ch0 + 0) / 19];
            float swv1 = sw[(ch0 + 1) / 19], sbv1 = sb[(ch0 + 1) / 19];
            float swv2 = sw[(ch0 + 2) / 19], sbv2 = sb[(ch0 + 2) / 19];
            float swv3 = sw[(ch0 + 3) / 19], sbv3 = sb[(ch0 + 3) / 19];
            const float* i0 = g_inp + (n * 19 + (ch0 + 0) % 19) * 1000;
            const float* i1 = g_inp + (n * 19 + (ch0 + 1) % 19) * 1000;
            const float* i2 = g_inp + (n * 19 + (ch0 + 2) % 19) * 1000;
            const float* i3 = g_inp + (n * 19 + (ch0 + 3) % 19) * 1000;
            for (int it = 0; it < 4; ++it) {
                int v = it * 256 + tid;
                if (v >= 1000) break;
                float4 t;
                t.x = swv0 * i0[v] + sbv0;
                t.y = swv1 * i1[v] + sbv1;
                t.z = swv2 * i2[v] + sbv2;
                t.w = swv3 * i3[v] + sbv3;
                dst[v] = t;
            }
        } else {
            for (int it = 0; it < 4; ++it) {
                int v = it * 256 + tid;
                if (v >= 1000) break;
                float4 t;
                t.x = X[gb + v];
                t.y = X[gb + 1000 + v];
                t.z = X[gb + 2000 + v];
                t.w = X[gb + 3000 + v];
                dst[v] = t;
            }
        }
    };

    // phase 1: stage X -> U
    stage_x(U4);
    __syncthreads();

    // phase 2: P1 = CSR(U) -> W
    csr_hop(Ub, W4);
    __syncthreads();

    // phase 3: writeback P1; P2 = CSR(W) -> U
    for (int it = 0; it < 4; ++it) {
        int v = it * 256 + tid;
        if (v >= 1000) break;
        float4 t = W4[v];
        o1[gb + v] = t.x;
        o1[gb + 1000 + v] = t.y;
        o1[gb + 2000 + v] = t.z;
        o1[gb + 3000 + v] = t.w;
    }
    csr_hop(Wb, U4);
    __syncthreads();

    // phase 4: writeback P2; restage X -> W (L3/L2-hot)
    for (int it = 0; it < 4; ++it) {
        int v = it * 256 + tid;
        if (v >= 1000) break;
        float4 t = U4[v];
        o2[gb + v] = t.x;
        o2[gb + 1000 + v] = t.y;
        o2[gb + 2000 + v] = t.z;
        o2[gb + 3000 + v] = t.w;
    }
    stage_x(W4);
    __syncthreads();

    // phase 5: Q1 = CSC(W) -> U
    csc_hop(Wb, U4);
    __syncthreads();

    // phase 6: writeback Q1; Q2 = CSC(U) -> W
    for (int it = 0; it < 4; ++it) {
        int v = it * 256 + tid;
        if (v >= 1000) break;
        float4 t = U4[v];
        o3[gb + v] = t.x;
        o3[gb + 1000 + v] = t.y;
        o3[gb + 2000 + v] = t.z;
        o3[gb + 3000 + v] = t.w;
    }
    csc_hop(Ub, W4);
    __syncthreads();

    // phase 7: writeback Q2
    for (int it = 0; it < 4; ++it) {
        int v = it * 256 + tid;
        if (v >= 1000) break;
        float4 t = W4[v];
        o4[gb + v] = t.x;
        o4[gb + 1000 + v] = t.y;
        o4[gb + 2000 + v] = t.z;
        o4[gb + 3000 + v] = t.w;
    }
}

// srcs are {X, P1=Mx, P2=M^2x, Q1=M'x, Q2=M'^2x}; alpha-mix folded into
// the weights (exact): with b=1-a,
//   wx' = wx + a*(w1+w2+w3+w4); wP1 = b*(w1+a*w2); wP2 = b^2*w2;
//   wQ1 = b*(w3+a*w4); wQ2 = b^2*w4.
// li0: X = sw[c]*inp+sb[c] broadcast -> st0 collapses to
//   inp[l][v]*sum_c(wx'[o][c]sw[c]) + sum_c(wx'[o][c]sb[c]).
__global__ __launch_bounds__(256) void k_mix(int xs, int h1s, int h2s, int h3s, int h4s, int ms,
                                             const float* __restrict__ g1w, const float* __restrict__ g2w,
                                             const float* __restrict__ g1b, const float* __restrict__ g2b,
                                             int P, int li0,
                                             const float* __restrict__ sw_,
                                             const float* __restrict__ sb_)
{
    __shared__ float sW[5 * 1024];
    __shared__ float sB[32];
    __shared__ float sWS[32];
    __shared__ float sSB[32];
    int tid = threadIdx.x;
    const float A = ALPHA_C, Bq = 1.f - ALPHA_C;
    for (int i = tid; i < 1024; i += 256) {
        int o = i >> 5, c = i & 31;
        float w1 = g1w[o * 96 + 32 + c], w2 = g1w[o * 96 + 64 + c];
        float w3 = g2w[o * 96 + 32 + c], w4 = g2w[o * 96 + 64 + c];
        sW[i]        = g1w[o * 96 + c] + g2w[o * 96 + c] + A * (w1 + w2 + w3 + w4);
        sW[1024 + i] = Bq * (w1 + A * w2);
        sW[2048 + i] = Bq * Bq * w2;
        sW[3072 + i] = Bq * (w3 + A * w4);
        sW[4096 + i] = Bq * Bq * w4;
    }
    if (tid < 32) sB[tid] = g1b[tid] + g2b[tid];
    __syncthreads();
    if (li0 && tid < 32) {
        float as = 0.f, ab = 0.f;
        for (int c = 0; c < 32; ++c) {
            float w = sW[tid * 32 + c];
            as += w * sw_[c];
            ab += w * sb_[c];
        }
        sWS[tid] = as;
        sSB[tid] = ab;
    }
    if (li0) __syncthreads();
    int n = blockIdx.y;
    int p = blockIdx.x * 256 + tid;
    if (p >= P) return;
    const float* srcs[5] = {bufsel(xs), bufsel(h1s), bufsel(h2s), bufsel(h3s), bufsel(h4s)};
    float acc[32];
    int st0;
    if (li0) {
        float xv = g_inp[(size_t)n * 19000 + p];
#pragma unroll
        for (int o = 0; o < 32; ++o) acc[o] = sB[o] + sSB[o] + sWS[o] * xv;
        st0 = 1;
    } else {
#pragma unroll
        for (int o = 0; o < 32; ++o) acc[o] = sB[o];
        st0 = 0;
    }
    for (int st = st0; st < 5; ++st) {
        const float* src = srcs[st] + (size_t)n * 32 * P + p;
        const float* w = &sW[st * 1024];
        for (int c = 0; c < 32; ++c) {
            float hv = src[(size_t)c * P];
#pragma unroll
            for (int o = 0; o < 32; ++o) acc[o] += w[o * 32 + c] * hv;
        }
    }
    float* XM = bufsel(ms) + (size_t)n * 32 * P + p;
#pragma unroll
    for (int o = 0; o < 32; ++o) XM[(size_t)o * P] = acc[o];
}

// inception + tanh*sigmoid + fused skip-conv (gated values kept in LDS)
template <int LIN>
__global__ __launch_bounds__(256) void k_incept(int xmsel, int xgsel,
                                                const float* __restrict__ fw2, const float* __restrict__ fw3,
                                                const float* __restrict__ fw6, const float* __restrict__ fw7,
                                                const float* __restrict__ fb,
                                                const float* __restrict__ gw2, const float* __restrict__ gw3,
                                                const float* __restrict__ gw6, const float* __restrict__ gw7,
                                                const float* __restrict__ gb,
                                                const float* __restrict__ skw, const float* __restrict__ skb)
{
    const int LOUT = LIN - 6;
    const float* XM = bufsel(xmsel);
    float* XG = bufsel(xgsel);
    __shared__ float sx[32 * 8 * LIN];
    __shared__ float sxg[32 * 8 * LOUT];
    int tid = threadIdx.x;
    int n = blockIdx.y, v0 = blockIdx.x * 8;
    for (int i = tid; i < 32 * LIN * 8; i += 256) {
        int vl = i & 7;
        int l = (i >> 3) % LIN;
        int c = i / (8 * LIN);
        sx[(c * 8 + vl) * LIN + l] = XM[(((size_t)n * 32 + c) * LIN + l) * 1000 + v0 + vl];
    }
    __syncthreads();
    int co = tid >> 3, vl = tid & 7;
    int s = co >> 3, co_s = co & 7;
    const int ksz[4] = {2, 3, 6, 7};
    int k = ksz[s];
    const float* fw = (s == 0) ? fw2 : ((s == 1) ? fw3 : ((s == 2) ? fw6 : fw7));
    const float* gw = (s == 0) ? gw2 : ((s == 1) ? gw3 : ((s == 2) ? gw6 : gw7));
    float accf[LOUT], accg[LOUT];
    float bf = fb[co], bg = gb[co];
#pragma unroll
    for (int l = 0; l < LOUT; ++l) { accf[l] = bf; accg[l] = bg; }
    for (int c = 0; c < 32; ++c) {
        const float* xp = &sx[(c * 8 + vl) * LIN];
        for (int j = 0; j < k; ++j) {
            float wf = fw[(co_s * 32 + c) * k + j];
            float wg = gw[(co_s * 32 + c) * k + j];
            int base = 7 - k + j;
#pragma unroll
            for (int l = 0; l < LOUT; ++l) {
                float xv = xp[base + l];
                accf[l] += wf * xv;
                accg[l] += wg * xv;
            }
        }
    }
    size_t ob = ((size_t)n * 32 + co) * LOUT * 1000 + v0 + vl;
#pragma unroll
    for (int l = 0; l < LOUT; ++l) {
        float g = tanhf(accf[l]) * (1.f / (1.f + expf(-accg[l])));
        XG[ob + (size_t)l * 1000] = g;
        sxg[(co * 8 + vl) * LOUT + l] = g;
    }
    __syncthreads();
    int obk = tid >> 3;
    for (int half = 0; half < 2; ++half) {
        int o = obk + 32 * half;
        float acc = skb[o];
        for (int c = 0; c < 32; ++c) {
            const float* wp = &skw[((size_t)o * 32 + c) * LOUT];
            const float* xp = &sxg[(c * 8 + vl) * LOUT];
#pragma unroll
            for (int l = 0; l < LOUT; ++l) acc += wp[l] * xp[l];
        }
        size_t si = ((size_t)n * 64 + o) * 1000 + v0 + vl;
        g_skip[si] += acc;
    }
}

__global__ __launch_bounds__(256) void k_resid_stats(int xnsel, int xpsel,
                                                     int li, int LIN, int LOUT, int li0,
                                                     const float* __restrict__ sw_,
                                                     const float* __restrict__ sb_)
{
    float* XN = bufsel(xnsel);
    const float* Xp = bufsel(xpsel);
    float* stats = g_stats + li * 64;
    int n = blockIdx.y;
    int S = 32 * LOUT * 1000;
    int tid = threadIdx.x;
    int gsz = gridDim.x * 256;
    float sum = 0.f, ss = 0.f;
    for (int idx = blockIdx.x * 256 + tid; idx < S; idx += gsz) {
        int v = idx % 1000;
        int l = (idx / 1000) % LOUT;
        int c = idx / (1000 * LOUT);
        float r;
        if (li0)
            r = sw_[c] * g_inp[(n * 19 + l + 6) * 1000 + v] + sb_[c];
        else
            r = Xp[(((size_t)n * 32 + c) * LIN + l + (LIN - LOUT)) * 1000 + v];
        float y = XN[(size_t)n * S + idx] + r;
        XN[(size_t)n * S + idx] = y;
        sum += y;
        ss += y * y;
    }
    __shared__ float s1[256], s2[256];
    s1[tid] = sum;
    s2[tid] = ss;
    __syncthreads();
    for (int s = 128; s > 0; s >>= 1) {
        if (tid < s) { s1[tid] += s1[tid + s]; s2[tid] += s2[tid + s]; }
        __syncthreads();
    }
    if (tid == 0) {
        atomicAdd(&stats[n * 2], s1[0]);
        atomicAdd(&stats[n * 2 + 1], s2[0]);
    }
}

__global__ void k_norm(int xnsel, const float* __restrict__ nw,
                       const float* __restrict__ nb, int li, int LOUT)
{
    float* XN = bufsel(xnsel);
    const float* stats = g_stats + li * 64;
    int S = 32 * LOUT * 1000;
    long long total = (long long)NBC * S;
    long long stride = (long long)gridDim.x * 256;
    for (long long i = (long long)blockIdx.x * 256 + threadIdx.x; i < total; i += stride) {
        int n = (int)(i / S);
        int rem = (int)(i % S);
        int v = rem % 1000;
        int l = (rem / 1000) % LOUT;
        int c = rem / (1000 * LOUT);
        int widx = (c * 1000 + v) * LOUT + l;
        float cnt = (float)S;
        float mu = stats[n * 2] / cnt;
        float var = stats[n * 2 + 1] / cnt - mu * mu;
        float rs = rsqrtf(var + EPS_C);
        XN[i] = (XN[i] - mu) * rs * nw[widx] + nb[widx];
    }
}

__global__ __launch_bounds__(256) void k_final(int xsel,
                                               const float* __restrict__ ew, const float* __restrict__ eb,
                                               const float* __restrict__ e1w, const float* __restrict__ e1b,
                                               const float* __restrict__ e2w, const float* __restrict__ e2b,
                                               float* __restrict__ out)
{
    const float* X = bufsel(xsel);
    __shared__ float sxf[32 * 16];
    __shared__ float sk[64 * 16];
    __shared__ float s1[64 * 16];
    __shared__ float s2[128 * 16];
    int b = blockIdx.y, v0 = blockIdx.x * 16;
    int tid = threadIdx.x;
    for (int i = tid; i < 512; i += 256) {
        int c = i / 16, vl = i & 15;
        int v = v0 + vl;
        sxf[i] = (v < 1000) ? X[((size_t)b * 32 + c) * 1000 + v] : 0.f;
    }
    for (int i = tid; i < 1024; i += 256) {
        int o = i / 16, vl = i & 15;
        int v = v0 + vl;
        sk[i] = (v < 1000) ? g_skip[((size_t)b * 64 + o) * 1000 + v] : 0.f;
    }
    __syncthreads();
    for (int i = tid; i < 1024; i += 256) {
        int o = i / 16, vl = i & 15;
        float acc = sk[i] + eb[o];
        for (int c = 0; c < 32; ++c) acc += ew[o * 32 + c] * sxf[c * 16 + vl];
        s1[i] = fmaxf(acc, 0.f);
    }
    __syncthreads();
    for (int i = tid; i < 2048; i += 256) {
        int o = i / 16, vl = i & 15;
        float acc = e1b[o];
        for (int c = 0; c < 64; ++c) acc += e1w[o * 64 + c] * s1[c * 16 + vl];
        s2[i] = fmaxf(acc, 0.f);
    }
    __syncthreads();
    if (tid < 192) {
        int o = tid / 16, vl = tid & 15;
        int v = v0 + vl;
        if (v < 1000) {
            float acc = e2b[o];
            for (int c = 0; c < 128; ++c) acc += e2w[o * 128 + c] * s2[c * 16 + vl];
            out[((size_t)b * 12 + o) * 1000 + v] = acc;
        }
    }
}

// ---------------- host ----------------

static const int SZ_SORT[43] = {240000,240000,128,8192,12,1536,96,1536,2304,4608,
                                5376,96,9216,96,9216,96,1536,2304,4608,5376,
                                480,19200,480,19200,416000,224000,32000,416000,224000,32000,
                                64,1216,64,2048,64,64,64,26624,14336,2048,32,32,768000};
static const int SZ_DICT[43] = {768000,32,32,1216,64,240000,240000,19200,480,19200,
                                480,9216,96,9216,96,1536,2304,4608,5376,96,
                                1536,2304,4608,5376,96,26624,64,416000,416000,14336,
                                64,224000,224000,2048,64,32000,32000,2048,64,8192,128,1536,12};
static const int SZ_SIG[43]  = {768000,32,32,1216,64,240000,240000,19200,480,19200,
                                480,9216,96,9216,96,1536,2304,4608,5376,96,
                                1536,2304,4608,5376,96,26624,64,14336,64,2048,
                                64,416000,416000,224000,224000,32000,32000,2048,64,8192,128,1536,12};

extern "C" void kernel_launch(void* const* d_in, const int* in_sizes, int n_in,
                              void* d_out, int out_size, void* d_ws, size_t ws_size,
                              hipStream_t stream)
{
    (void)d_ws; (void)ws_size;
    const float *x_in, *start_w, *start_b, *skip0_w, *skip0_b;
    const float *emb1, *emb2, *lin1_w, *lin1_b, *lin2_w, *lin2_b;
    const float *g1_w, *g1_b, *g2_w, *g2_b;
    const float *filt_w[4], *filt_b, *gate_w[4], *gate_b;
    const float *skw[3], *skb[3], *nww[3], *nbb[3];
    const float *skipE_w, *skipE_b, *end1_w, *end1_b, *end2_w, *end2_b;
    float* outp = (float*)d_out;
    auto P = [&](int i) { return (const float*)d_in[i]; };
    auto match = [&](const int* tab) {
        if (n_in < 43) return false;
        for (int i = 0; i < 43; ++i) if (in_sizes[i] != tab[i]) return false;
        return true;
    };

    int fam = -1;
    if (match(SZ_SORT)) fam = 0;
    else if (match(SZ_DICT)) fam = 1;
    else if (match(SZ_SIG)) fam = 2;

    if (fam == 0) {
        emb1 = P(0); emb2 = P(1); end1_b = P(2); end1_w = P(3); end2_b = P(4); end2_w = P(5);
        filt_b = P(6); filt_w[0] = P(7); filt_w[1] = P(8); filt_w[2] = P(9); filt_w[3] = P(10);
        g1_b = P(11); g1_w = P(12); g2_b = P(13); g2_w = P(14);
        gate_b = P(15); gate_w[0] = P(16); gate_w[1] = P(17); gate_w[2] = P(18); gate_w[3] = P(19);
        lin1_b = P(20); lin1_w = P(21); lin2_b = P(22); lin2_w = P(23);
        nbb[0] = P(24); nbb[1] = P(25); nbb[2] = P(26);
        nww[0] = P(27); nww[1] = P(28); nww[2] = P(29);
        skip0_b = P(30); skip0_w = P(31); skipE_b = P(32); skipE_w = P(33);
        skb[0] = P(34); skb[1] = P(35); skb[2] = P(36);
        skw[0] = P(37); skw[1] = P(38); skw[2] = P(39);
        start_b = P(40); start_w = P(41); x_in = P(42);
    } else if (fam == 1 || fam == 2) {
        x_in = P(0); start_w = P(1); start_b = P(2); skip0_w = P(3); skip0_b = P(4);
        emb1 = P(5); emb2 = P(6); lin1_w = P(7); lin1_b = P(8); lin2_w = P(9); lin2_b = P(10);
        g1_w = P(11); g1_b = P(12); g2_w = P(13); g2_b = P(14);
        filt_w[0] = P(15); filt_w[1] = P(16); filt_w[2] = P(17); filt_w[3] = P(18); filt_b = P(19);
        gate_w[0] = P(20); gate_w[1] = P(21); gate_w[2] = P(22); gate_w[3] = P(23); gate_b = P(24);
        if (fam == 1) {
            skw[0] = P(25); skb[0] = P(26); nww[0] = P(27); nbb[0] = P(28);
            skw[1] = P(29); skb[1] = P(30); nww[1] = P(31); nbb[1] = P(32);
            skw[2] = P(33); skb[2] = P(34); nww[2] = P(35); nbb[2] = P(36);
        } else {
            skw[0] = P(25); skb[0] = P(26); skw[1] = P(27); skb[1] = P(28);
            skw[2] = P(29); skb[2] = P(30);
            nww[0] = P(31); nbb[0] = P(32); nww[1] = P(33); nbb[1] = P(34);
            nww[2] = P(35); nbb[2] = P(36);
        }
        skipE_w = P(37); skipE_b = P(38); end1_w = P(39); end1_b = P(40);
        end2_w = P(41); end2_b = P(42);
    } else {
        k_out_zero<<<(out_size + 255) / 256, 256, 0, stream>>>(outp, out_size);
        k_marker<<<1, 64, 0, stream>>>(outp, 8192.0f);
        return;
    }

    // ---- setup ----
    k_init<<<12, 256, 0, stream>>>();
    k_build_inp<<<(32 * 19 * 1000 + 255) / 256, 256, 0, stream>>>(x_in);
    k_nv<<<(240000 + 255) / 256, 256, 0, stream>>>(emb1, emb2, lin1_w, lin1_b, lin2_w, lin2_b);
    k_adj_topk<<<3000, 256, 0, stream>>>();
    k_scan<<<3, 256, 0, stream>>>();
    k_permsort<<<3, 256, 0, stream>>>();
    k_scatter<<<(60000 + 255) / 256, 256, 0, stream>>>();
    k_packT1<<<(60000 + 255) / 256, 256, 0, stream>>>();
    k_packT2<<<12, 256, 0, stream>>>();

    // ---- full-batch pipeline (k_start folded into prop4/mix/resid li0) ----
    k_skip0<<<dim3(32, NBC), 256, 0, stream>>>(skip0_w, skip0_b);

    int X = 0;   // layer-0 "X buffer" is virtual (affine of g_inp)
    int LIN = 19;
    for (int li = 0; li < 3; ++li) {
        int LOUT = LIN - 6;
        int Pp = 1000 * LIN;
        int li0 = (li == 0) ? 1 : 0;
        int hb[4], hn = 0;
        for (int b = 0; b < 6 && hn < 4; ++b)
            if (b != X && b != 1) hb[hn++] = b;
        int h1 = hb[0], h2 = hb[1], h3 = hb[2], h4 = hb[3];
        int CH = 32 * LIN;
        dim3 gg((unsigned)(CH / 4), NBC);

        // all 4 hops in one launch: o1=P1, o2=P2, o3=Q1, o4=Q2
        k_prop4<<<gg, 256, 0, stream>>>(X, h1, h2, h3, h4, li, CH, li0, start_w, start_b);

        k_mix<<<dim3((Pp + 255) / 256, NBC), 256, 0, stream>>>(X, h1, h2, h3, h4, 1,
            g1_w + li * 3072, g2_w + li * 3072, g1_b + li * 32, g2_b + li * 32, Pp,
            li0, start_w, start_b);

        int XG = h1;
        if (LIN == 19)
            k_incept<19><<<dim3(125, NBC), 256, 0, stream>>>(1, XG,
                filt_w[0] + li * 512, filt_w[1] + li * 768, filt_w[2] + li * 1536, filt_w[3] + li * 1792,
                filt_b + li * 32,
                gate_w[0] + li * 512, gate_w[1] + li * 768, gate_w[2] + li * 1536, gate_w[3] + li * 1792,
                gate_b + li * 32, skw[li], skb[li]);
        else if (LIN == 13)
            k_incept<13><<<dim3(125, NBC), 256, 0, stream>>>(1, XG,
                filt_w[0] + li * 512, filt_w[1] + li * 768, filt_w[2] + li * 1536, filt_w[3] + li * 1792,
                filt_b + li * 32,
                gate_w[0] + li * 512, gate_w[1] + li * 768, gate_w[2] + li * 1536, gate_w[3] + li * 1792,
                gate_b + li * 32, skw[li], skb[li]);
        else
            k_incept<7><<<dim3(125, NBC), 256, 0, stream>>>(1, XG,
                filt_w[0] + li * 512, filt_w[1] + li * 768, filt_w[2] + li * 1536, filt_w[3] + li * 1792,
                filt_b + li * 32,
                gate_w[0] + li * 512, gate_w[1] + li * 768, gate_w[2] + li * 1536, gate_w[3] + li * 1792,
                gate_b + li * 32, skw[li], skb[li]);

        k_resid_stats<<<dim3(16, NBC), 256, 0, stream>>>(XG, X, li, LIN, LOUT,
                                                         li0, start_w, start_b);
        k_norm<<<2048, 256, 0, stream>>>(XG, nww[li], nbb[li], li, LOUT);

        X = XG;
        LIN = LOUT;
    }
    k_final<<<dim3(63, NBC), 256, 0, stream>>>(X, skipE_w, skipE_b,
                                               end1_w, end1_b, end2_w, end2_b, outp);
}

// Round 10
// 2617.702 us; speedup vs baseline: 1.0453x; 1.0203x over previous
//
#include <hip/hip_runtime.h>
#include <math.h>

// CoGNN forward. Round 39 (best = r36 2654us; r38 2671 ~ noise).
// Pass-deletion round: (1) prop4 restructured - P2/Q2 are terminal, so
// CSR hops store to global from registers inline (coalesced); X stays in
// U through Q1 (phase-4 restage deleted); 2 LDS-readback passes and 1
// barrier deleted (6->5 syncs). (2) k_resid_stats folded into k_incept
// (residual add + y-write + shfl-reduced stats atomics; skip-conv still
// uses pre-residual gated value per reference). 3 launches + a full
// XG read/write pass per layer deleted. Everything else = r38 (li0
// folding, shfl topk, float4 dots, per-lane float4 gathers, pure powers,
// alpha folded into k_mix, 256thr/bounds(256,5) prop4 per r37 A/B).
// B=32,C=32,V=1000,L:19->13->7->1. fp32.

#define ALPHA_C 0.05f
#define EPS_C 1e-5f
#define NBC 32
#define CSCT_CAP 140000

// ---------------- static device workspace ----------------
__device__ float g_inp[32 * 19 * 1000];
__device__ float g_skip[32 * 64 * 1000];
__device__ __align__(16) float g_nv1[240000];
__device__ __align__(16) float g_nv2[240000];
__device__ __align__(16) int   g_tkcol[60000];
__device__ __align__(16) float g_tkval[60000];
__device__ float g_inv1[3000];
__device__ int   g_colcnt[3000];
__device__ float g_colsum[3000];
__device__ int   g_rp2[3 * 1001 + 1];
__device__ int   g_fill[3000];
__device__ int   g_cscr[60000];
__device__ float g_cscv[60000];
__device__ float g_inv2[3000];
__device__ float g_stats[3 * 64];
__device__ __align__(16) int2 g_pk1T[60000];        // CSR transposed [li][j][v] = (col*16, w)
__device__ __align__(16) int2 g_cscT[3 * CSCT_CAP]; // CSC tiled-transposed (row*16, w)
__device__ int   g_perm[3 * 1024];   // [li][rank] -> v (global degree desc; -1 sentinel)
__device__ int   g_degT[3 * 1024];   // [li][rank] -> degree
__device__ int   g_iperm[3 * 1000];  // [li][v] -> rank
__device__ int   g_tOff[3 * 17];     // [li][tile] -> cscT base offset
__device__ float g_B0[(size_t)NBC * 32 * 19 * 1000];
__device__ float g_B1[(size_t)NBC * 32 * 19 * 1000];
__device__ float g_B2[(size_t)NBC * 32 * 19 * 1000];
__device__ float g_B3[(size_t)NBC * 32 * 19 * 1000];
__device__ float g_B4[(size_t)NBC * 32 * 19 * 1000];
__device__ float g_B5[(size_t)NBC * 32 * 19 * 1000];

__device__ __forceinline__ float* bufsel(int s)
{
    switch (s) {
        case 0: return g_B0;
        case 1: return g_B1;
        case 2: return g_B2;
        case 3: return g_B3;
        case 4: return g_B4;
        default: return g_B5;
    }
}

__global__ void k_init()
{
    int i = blockIdx.x * 256 + threadIdx.x;
    if (i < 3000) { g_colcnt[i] = 0; g_colsum[i] = 0.f; g_fill[i] = 0; }
    if (i < 192) g_stats[i] = 0.f;
}

__global__ void k_out_zero(float* __restrict__ out, int n)
{
    int i = blockIdx.x * 256 + threadIdx.x;
    if (i < n) out[i] = 0.0f;
}

__global__ void k_marker(float* __restrict__ out, float v)
{
    if (threadIdx.x == 0) out[0] = v;
}

// ---------------- setup ----------------

__global__ void k_build_inp(const float* __restrict__ xin)
{
    int i = blockIdx.x * 256 + threadIdx.x;
    if (i >= 32 * 19 * 1000) return;
    int v = i % 1000;
    int t = (i / 1000) % 19;
    int b = i / 19000;
    float val = 0.f;
    if (t >= 7) {
        int tt = t - 7;
        int n = (v < 500) ? v : v - 500;
        int f = (v < 500) ? 0 : 1;
        val = xin[((b * 12 + tt) * 500 + n) * 4 + f];
    }
    g_inp[i] = val;
}

__global__ void k_nv(const float* __restrict__ e1, const float* __restrict__ e2,
                     const float* __restrict__ w1, const float* __restrict__ b1,
                     const float* __restrict__ w2, const float* __restrict__ b2)
{
    int i = blockIdx.x * 256 + threadIdx.x;
    if (i >= 12 * 500 * 40) return;
    int o = i % 40;
    int n = (i / 40) % 500;
    int m = i / (40 * 500);
    const float4* p1 = (const float4*)(e1 + (m * 500 + n) * 40);
    const float4* pw1 = (const float4*)(w1 + (m * 40 + o) * 40);
    const float4* p2 = (const float4*)(e2 + (m * 500 + n) * 40);
    const float4* pw2 = (const float4*)(w2 + (m * 40 + o) * 40);
    float a1 = b1[m * 40 + o], a2 = b2[m * 40 + o];
    for (int d = 0; d < 10; ++d) {
        float4 x1 = p1[d], y1 = pw1[d];
        float4 x2 = p2[d], y2 = pw2[d];
        a1 += x1.x * y1.x; a1 += x1.y * y1.y; a1 += x1.z * y1.z; a1 += x1.w * y1.w;
        a2 += x2.x * y2.x; a2 += x2.y * y2.y; a2 += x2.z * y2.z; a2 += x2.w * y2.w;
    }
    g_nv1[i] = a1;
    g_nv2[i] = a2;
}

__global__ __launch_bounds__(256) void k_adj_topk()
{
    __shared__ float row[1000];
    __shared__ float wvv[4];
    __shared__ int wvi[4];
    __shared__ int selc[20];
    __shared__ float selv[20];
    int li = blockIdx.x / 1000;
    int r = blockIdx.x % 1000;
    int tid = threadIdx.x;
    int wv = tid >> 6, lane = tid & 63;
    int bi = r / 500, n = r % 500;
    for (int c = tid; c < 1000; c += 256) {
        int bj = c / 500, k = c % 500;
        int mg = li * 4 + 2 * bi + bj;
        const float4* a = (const float4*)(g_nv1 + (mg * 500 + n) * 40);
        const float4* b = (const float4*)(g_nv2 + (mg * 500 + k) * 40);
        float acc = 0.f;
#pragma unroll
        for (int d = 0; d < 10; ++d) {
            float4 av = a[d], bv = b[d];
            acc += av.x * bv.x; acc += av.y * bv.y;
            acc += av.z * bv.z; acc += av.w * bv.w;
        }
        row[c] = acc;
    }
    __syncthreads();
    for (int sel = 0; sel < 20; ++sel) {
        float bv = -INFINITY;
        int bidx = 0;
        for (int c = tid; c < 1000; c += 256) {
            float x = row[c];
            if (x > bv) { bv = x; bidx = c; }
        }
#pragma unroll
        for (int m = 1; m < 64; m <<= 1) {
            float ov = __shfl_xor(bv, m);
            int oi = __shfl_xor(bidx, m);
            if (ov > bv || (ov == bv && oi < bidx)) { bv = ov; bidx = oi; }
        }
        if (lane == 0) { wvv[wv] = bv; wvi[wv] = bidx; }
        __syncthreads();
        if (tid == 0) {
            float fv = wvv[0];
            int fi = wvi[0];
#pragma unroll
            for (int k = 1; k < 4; ++k) {
                float ov = wvv[k];
                int oi = wvi[k];
                if (ov > fv || (ov == fv && oi < fi)) { fv = ov; fi = oi; }
            }
            int ci = fi;
            if (ci < 0 || ci > 999) ci = sel;
            selc[sel] = ci;
            selv[sel] = fv;
            g_tkcol[(li * 1000 + r) * 20 + sel] = ci;
            g_tkval[(li * 1000 + r) * 20 + sel] = fv;
            row[ci] = -INFINITY;
        }
        __syncthreads();
    }
    if (tid < 20) {
        atomicAdd(&g_colcnt[li * 1000 + selc[tid]], 1);
        atomicAdd(&g_colsum[li * 1000 + selc[tid]], selv[tid]);
    }
    if (tid == 0) {
        float s = 0.f;
        for (int j = 0; j < 20; ++j) s += selv[j];
        g_inv1[li * 1000 + r] = 1.f / (s + 1.f);
    }
}

__global__ __launch_bounds__(256) void k_scan()
{
    __shared__ int s[1000];
    int li = blockIdx.x;
    int tid = threadIdx.x;
    for (int i = tid; i < 1000; i += 256) s[i] = g_colcnt[li * 1000 + i];
    __syncthreads();
    if (tid == 0) {
        int run = 0;
        for (int i = 0; i < 1000; ++i) { int c = s[i]; s[i] = run; run += c; }
        g_rp2[li * 1001 + 1000] = run;
    }
    __syncthreads();
    for (int i = tid; i < 1000; i += 256) {
        g_rp2[li * 1001 + i] = s[i];
        g_inv2[li * 1000 + i] = 1.f / (g_colsum[li * 1000 + i] + 1.f);
    }
}

// global exact degree rank sort (desc, ties by index) + tile offsets
__global__ __launch_bounds__(256) void k_permsort()
{
    __shared__ int deg[1000];
    __shared__ int tmax[16];
    int li = blockIdx.x;
    int tid = threadIdx.x;
    for (int v = tid; v < 1000; v += 256)
        deg[v] = g_rp2[li * 1001 + v + 1] - g_rp2[li * 1001 + v];
    __syncthreads();
    for (int v = tid; v < 1000; v += 256) {
        int d = deg[v];
        int r = 0;
        for (int u = 0; u < 1000; ++u) {
            int du = deg[u];
            r += (du > d) || (du == d && u < v);
        }
        g_perm[li * 1024 + r] = v;
        g_degT[li * 1024 + r] = d;
        g_iperm[li * 1000 + v] = r;
        if ((r & 63) == 0) tmax[r >> 6] = d;
    }
    if (tid < 24) {
        g_perm[li * 1024 + 1000 + tid] = -1;
        g_degT[li * 1024 + 1000 + tid] = 0;
    }
    __syncthreads();
    if (tid == 0) {
        int off = 0;
        for (int t = 0; t < 16; ++t) {
            g_tOff[li * 17 + t] = off;
            off += 64 * tmax[t];
        }
        g_tOff[li * 17 + 16] = off;
    }
}

__global__ void k_scatter()
{
    int i = blockIdx.x * 256 + threadIdx.x;
    if (i >= 3 * 20000) return;
    int li = i / 20000;
    int e = i % 20000;
    int r = e / 20;
    int c = g_tkcol[i];
    if (c < 0) c = 0;
    if (c > 999) c = 999;
    float v = g_tkval[i];
    int pos = g_rp2[li * 1001 + c] + atomicAdd(&g_fill[li * 1000 + c], 1);
    if (pos < 0) pos = 0;
    if (pos > 19999) pos = 19999;
    g_cscr[li * 20000 + pos] = r;
    g_cscv[li * 20000 + pos] = v;
}

// transposed CSR pack: pk1T[li][j][v] = (col*16, w)  (byte-premult for float4)
__global__ void k_packT1()
{
    int i = blockIdx.x * 256 + threadIdx.x;
    if (i >= 60000) return;
    int li = i / 20000;
    int e = i % 20000;
    int v = e / 20, j = e % 20;
    int c1 = g_tkcol[i];
    if (c1 < 0) c1 = 0;
    if (c1 > 999) c1 = 999;
    g_pk1T[li * 20000 + j * 1000 + v] = make_int2(c1 * 16, __float_as_int(g_tkval[i]));
}

// tiled-transposed CSC pack: cscT[tOff[t] + j*64 + lane] = (row*16, w)
__global__ void k_packT2()
{
    int i = blockIdx.x * 256 + threadIdx.x;
    if (i >= 3000) return;
    int li = i / 1000, v = i % 1000;
    int r = g_iperm[li * 1000 + v];
    int t = r >> 6, ln = r & 63;
    int j0 = g_rp2[li * 1001 + v];
    int d = g_rp2[li * 1001 + v + 1] - j0;
    int base = g_tOff[li * 17 + t];
    for (int j = 0; j < d; ++j) {
        int row = g_cscr[li * 20000 + j0 + j];
        if (row < 0) row = 0;
        if (row > 999) row = 999;
        int pos = base + j * 64 + ln;
        if (pos >= 0 && pos < CSCT_CAP)
            g_cscT[li * CSCT_CAP + pos] =
                make_int2(row * 16, __float_as_int(g_cscv[li * 20000 + j0 + j]));
    }
}

// ---------------- pipeline kernels ([n][ch][v] layout, ch = c*L + l) ----------------

__global__ __launch_bounds__(256) void k_skip0(const float* __restrict__ w,
                                               const float* __restrict__ bb)
{
    __shared__ float s_inp[19 * 32];
    __shared__ float s_w[64 * 19];
    int b = blockIdx.y;
    int v0 = blockIdx.x * 32;
    int tid = threadIdx.x;
    for (int i = tid; i < 64 * 19; i += 256) s_w[i] = w[i];
    for (int i = tid; i < 19 * 32; i += 256) {
        int t = i / 32, vl = i % 32;
        int v = v0 + vl;
        s_inp[i] = (v < 1000) ? g_inp[(b * 19 + t) * 1000 + v] : 0.f;
    }
    __syncthreads();
    for (int e = tid; e < 64 * 32; e += 256) {
        int o = e / 32, vl = e % 32;
        int v = v0 + vl;
        if (v >= 1000) continue;
        float acc = bb[o];
#pragma unroll
        for (int t = 0; t < 19; ++t) acc += s_w[o * 19 + t] * s_inp[t * 32 + vl];
        g_skip[(b * 64 + o) * 1000 + v] = acc;
    }
}

// All 4 mixprop hops, one launch, CH_BLK=4 channels per block (float4/col).
// Pass-reduced schedule (P2/Q2 terminal -> no LDS write; X stays in U):
//  1 stage X->U | 2 P1=csr(U)->W + inline store | 3 P2=csr(W) store-only |
//  4 Q1=csc(U)->W | 5 store o3 from W + Q2=csc(W)->U | 6 store o4 from U.
// 5 barriers (was 6), no restage, no CSR LDS-readback passes.
__global__ __launch_bounds__(256, 5) void k_prop4(int xsel, int o1s, int o2s, int o3s, int o4s,
                                                  int li, int CH, int li0,
                                                  const float* __restrict__ sw,
                                                  const float* __restrict__ sb)
{
    __shared__ float4 S[2000];   // U = S[0..999], W = S[1000..1999]
    const float* X = bufsel(xsel);
    float* o1 = bufsel(o1s);
    float* o2 = bufsel(o2s);
    float* o3 = bufsel(o3s);
    float* o4 = bufsel(o4s);
    const int2* pkT = g_pk1T + li * 20000;
    const int2* cT = g_cscT + (size_t)li * CSCT_CAP;
    const int* prm = g_perm + li * 1024;
    const int* dgT = g_degT + li * 1024;
    const int* tOf = g_tOff + li * 17;
    const float* iv1 = g_inv1 + li * 1000;
    const float* iv2 = g_inv2 + li * 1000;
    int n = blockIdx.y;
    int ch0 = blockIdx.x * 4;
    size_t gb = ((size_t)n * CH + ch0) * 1000;
    int tid = threadIdx.x;
    int wv = tid >> 6, lane = tid & 63;
    char* Ub = (char*)S;
    char* Wb = (char*)(S + 1000);
    float4* U4 = S;
    float4* W4 = S + 1000;

    // CSR hop: res[v] = (src[v] + sum_j w_j src[col_j]) * iv1[v];
    // optional LDS write (dst) + inline coalesced global store (gout).
    auto csr_hop = [&](const char* sbuf, float4* dst, float* gout) {
        for (int it = 0; it < 4; ++it) {
            int v = it * 256 + tid;
            if (v >= 1000) break;
            const int2* mp = pkT + v;
            float4 a = *(const float4*)(sbuf + (size_t)v * 16);
#pragma unroll
            for (int jb = 0; jb < 5; ++jb) {
                int2 e0 = mp[(jb * 4 + 0) * 1000];
                int2 e1 = mp[(jb * 4 + 1) * 1000];
                int2 e2 = mp[(jb * 4 + 2) * 1000];
                int2 e3 = mp[(jb * 4 + 3) * 1000];
                float w0 = __int_as_float(e0.y), w1 = __int_as_float(e1.y);
                float w2 = __int_as_float(e2.y), w3 = __int_as_float(e3.y);
                float4 x0 = *(const float4*)(sbuf + e0.x);
                float4 x1 = *(const float4*)(sbuf + e1.x);
                float4 x2 = *(const float4*)(sbuf + e2.x);
                float4 x3 = *(const float4*)(sbuf + e3.x);
                a.x += w0 * x0.x + w1 * x1.x + w2 * x2.x + w3 * x3.x;
                a.y += w0 * x0.y + w1 * x1.y + w2 * x2.y + w3 * x3.y;
                a.z += w0 * x0.z + w1 * x1.z + w2 * x2.z + w3 * x3.z;
                a.w += w0 * x0.w + w1 * x1.w + w2 * x2.w + w3 * x3.w;
            }
            float s = iv1[v];
            a.x *= s; a.y *= s; a.z *= s; a.w *= s;
            if (dst) dst[v] = a;
            gout[gb + v] = a.x;
            gout[gb + 1000 + v] = a.y;
            gout[gb + 2000 + v] = a.z;
            gout[gb + 3000 + v] = a.w;
        }
    };

    // CSC hop: dst[v] = (src[v] + sum_j w_j src[row_j]) * iv2[v] (scattered)
    auto csc_hop = [&](const char* sbuf, float4* dst) {
        for (int o = 0; o < 4; ++o) {
            int tile = o * 4 + ((o & 1) ? (3 - wv) : wv);   // snake balance
            int r = tile * 64 + lane;
            int v = prm[r];
            if (v < 0) continue;
            int d = dgT[r];
            const int2* mp = cT + tOf[tile] + lane;
            float4 a = *(const float4*)(sbuf + (size_t)v * 16);
            int j = 0;
            for (; j + 4 <= d; j += 4) {
                int2 e0 = mp[(j + 0) * 64];
                int2 e1 = mp[(j + 1) * 64];
                int2 e2 = mp[(j + 2) * 64];
                int2 e3 = mp[(j + 3) * 64];
                float w0 = __int_as_float(e0.y), w1 = __int_as_float(e1.y);
                float w2 = __int_as_float(e2.y), w3 = __int_as_float(e3.y);
                float4 x0 = *(const float4*)(sbuf + e0.x);
                float4 x1 = *(const float4*)(sbuf + e1.x);
                float4 x2 = *(const float4*)(sbuf + e2.x);
                float4 x3 = *(const float4*)(sbuf + e3.x);
                a.x += w0 * x0.x + w1 * x1.x + w2 * x2.x + w3 * x3.x;
                a.y += w0 * x0.y + w1 * x1.y + w2 * x2.y + w3 * x3.y;
                a.z += w0 * x0.z + w1 * x1.z + w2 * x2.z + w3 * x3.z;
                a.w += w0 * x0.w + w1 * x1.w + w2 * x2.w + w3 * x3.w;
            }
            for (; j < d; ++j) {
                int2 e = mp[j * 64];
                float w = __int_as_float(e.y);
                float4 x = *(const float4*)(sbuf + e.x);
                a.x += w * x.x; a.y += w * x.y; a.z += w * x.z; a.w += w * x.w;
            }
            float s = iv2[v];
            a.x *= s; a.y *= s; a.z *= s; a.w *= s;
            dst[v] = a;
        }
    };

    // phase 1: stage X -> U (li0: affine of g_inp, else global read)
    if (li0) {
        float swv0 = sw[(ch0 + 0) / 19], sbv0 = sb[(ch0 + 0) / 19];
        float swv1 = sw[(ch0 + 1) / 19], sbv1 = sb[(ch0 + 1) / 19];
        float swv2 = sw[(ch0 + 2) / 19], sbv2 = sb[(ch0 + 2) / 19];
        float swv3 = sw[(ch0 + 3) / 19], sbv3 = sb[(ch0 + 3) / 19];
        const float* i0 = g_inp + (n * 19 + (ch0 + 0) % 19) * 1000;
        const float* i1 = g_inp + (n * 19 + (ch0 + 1) % 19) * 1000;
        const float* i2 = g_inp + (n * 19 + (ch0 + 2) % 19) * 1000;
        const float* i3 = g_inp + (n * 19 + (ch0 + 3) % 19) * 1000;
        for (int it = 0; it < 4; ++it) {
            int v = it * 256 + tid;
            if (v >= 1000) break;
            float4 t;
            t.x = swv0 * i0[v] + sbv0;
            t.y = swv1 * i1[v] + sbv1;
            t.z = swv2 * i2[v] + sbv2;
            t.w = swv3 * i3[v] + sbv3;
            U4[v] = t;
        }
    } else {
        for (int it = 0; it < 4; ++it) {
            int v = it * 256 + tid;
            if (v >= 1000) break;
            float4 t;
            t.x = X[gb + v];
            t.y = X[gb + 1000 + v];
            t.z = X[gb + 2000 + v];
            t.w = X[gb + 3000 + v];
            U4[v] = t;
        }
    }
    __syncthreads();

    // phase 2: P1 = CSR(U) -> W + inline store o1
    csr_hop(Ub, W4, o1);
    __syncthreads();

    // phase 3: P2 = CSR(W) -> store o2 only (terminal; U=X preserved)
    csr_hop(Wb, (float4*)nullptr, o2);
    __syncthreads();

    // phase 4: Q1 = CSC(U) -> W (scattered; overwrites P1 after sync)
    csc_hop(Ub, W4);
    __syncthreads();

    // phase 5: coalesced store o3 from W; Q2 = CSC(W) -> U (terminal in LDS)
    for (int it = 0; it < 4; ++it) {
        int v = it * 256 + tid;
        if (v >= 1000) break;
        float4 t = W4[v];
        o3[gb + v] = t.x;
        o3[gb + 1000 + v] = t.y;
        o3[gb + 2000 + v] = t.z;
        o3[gb + 3000 + v] = t.w;
    }
    csc_hop(Wb, U4);
    __syncthreads();

    // phase 6: coalesced store o4 from U
    for (int it = 0; it < 4; ++it) {
        int v = it * 256 + tid;
        if (v >= 1000) break;
        float4 t = U4[v];
        o4[gb + v] = t.x;
        o4[gb + 1000 + v] = t.y;
        o4[gb + 2000 + v] = t.z;
        o4[gb + 3000 + v] = t.w;
    }
}

// srcs are {X, P1=Mx, P2=M^2x, Q1=M'x, Q2=M'^2x}; alpha-mix folded into
// the weights (exact): with b=1-a,
//   wx' = wx + a*(w1+w2+w3+w4); wP1 = b*(w1+a*w2); wP2 = b^2*w2;
//   wQ1 = b*(w3+a*w4); wQ2 = b^2*w4.
// li0: X = sw[c]*inp+sb[c] broadcast -> st0 collapses to
//   inp[l][v]*sum_c(wx'[o][c]sw[c]) + sum_c(wx'[o][c]sb[c]).
__global__ __launch_bounds__(256) void k_mix(int xs, int h1s, int h2s, int h3s, int h4s, int ms,
                                             const float* __restrict__ g1w, const float* __restrict__ g2w,
                                             const float* __restrict__ g1b, const float* __restrict__ g2b,
                                             int P, int li0,
                                             const float* __restrict__ sw_,
                                             const float* __restrict__ sb_)
{
    __shared__ float sW[5 * 1024];
    __shared__ float sB[32];
    __shared__ float sWS[32];
    __shared__ float sSB[32];
    int tid = threadIdx.x;
    const float A = ALPHA_C, Bq = 1.f - ALPHA_C;
    for (int i = tid; i < 1024; i += 256) {
        int o = i >> 5, c = i & 31;
        float w1 = g1w[o * 96 + 32 + c], w2 = g1w[o * 96 + 64 + c];
        float w3 = g2w[o * 96 + 32 + c], w4 = g2w[o * 96 + 64 + c];
        sW[i]        = g1w[o * 96 + c] + g2w[o * 96 + c] + A * (w1 + w2 + w3 + w4);
        sW[1024 + i] = Bq * (w1 + A * w2);
        sW[2048 + i] = Bq * Bq * w2;
        sW[3072 + i] = Bq * (w3 + A * w4);
        sW[4096 + i] = Bq * Bq * w4;
    }
    if (tid < 32) sB[tid] = g1b[tid] + g2b[tid];
    __syncthreads();
    if (li0 && tid < 32) {
        float as = 0.f, ab = 0.f;
        for (int c = 0; c < 32; ++c) {
            float w = sW[tid * 32 + c];
            as += w * sw_[c];
            ab += w * sb_[c];
        }
        sWS[tid] = as;
        sSB[tid] = ab;
    }
    if (li0) __syncthreads();
    int n = blockIdx.y;
    int p = blockIdx.x * 256 + tid;
    if (p >= P) return;
    const float* srcs[5] = {bufsel(xs), bufsel(h1s), bufsel(h2s), bufsel(h3s), bufsel(h4s)};
    float acc[32];
    int st0;
    if (li0) {
        float xv = g_inp[(size_t)n * 19000 + p];
#pragma unroll
        for (int o = 0; o < 32; ++o) acc[o] = sB[o] + sSB[o] + sWS[o] * xv;
        st0 = 1;
    } else {
#pragma unroll
        for (int o = 0; o < 32; ++o) acc[o] = sB[o];
        st0 = 0;
    }
    for (int st = st0; st < 5; ++st) {
        const float* src = srcs[st] + (size_t)n * 32 * P + p;
        const float* w = &sW[st * 1024];
        for (int c = 0; c < 32; ++c) {
            float hv = src[(size_t)c * P];
#pragma unroll
            for (int o = 0; o < 32; ++o) acc[o] += w[o * 32 + c] * hv;
        }
    }
    float* XM = bufsel(ms) + (size_t)n * 32 * P + p;
#pragma unroll
    for (int o = 0; o < 32; ++o) XM[(size_t)o * P] = acc[o];
}

// inception + tanh*sigmoid + fused skip-conv + FUSED residual & layernorm
// stats (sum/sumsq via shfl reduce + 2 atomics/block). Skip conv uses the
// pre-residual gated value (reference semantics); XG receives y = g + resid.
template <int LIN>
__global__ __launch_bounds__(256) void k_incept(int xmsel, int xgsel, int xpsel,
                                                const float* __restrict__ fw2, const float* __restrict__ fw3,
                                                const float* __restrict__ fw6, const float* __restrict__ fw7,
                                                const float* __restrict__ fb,
                                                const float* __restrict__ gw2, const float* __restrict__ gw3,
                                                const float* __restrict__ gw6, const float* __restrict__ gw7,
                                                const float* __restrict__ gb,
                                                const float* __restrict__ skw, const float* __restrict__ skb,
                                                int li, int li0,
                                                const float* __restrict__ sw_,
                                                const float* __restrict__ sb_)
{
    const int LOUT = LIN - 6;
    const float* XM = bufsel(xmsel);
    float* XG = bufsel(xgsel);
    const float* Xp = bufsel(xpsel);
    float* stats = g_stats + li * 64;
    __shared__ float sx[32 * 8 * LIN];
    __shared__ float sxg[32 * 8 * LOUT];
    __shared__ float ws1[4], ws2[4];
    int tid = threadIdx.x;
    int n = blockIdx.y, v0 = blockIdx.x * 8;
    for (int i = tid; i < 32 * LIN * 8; i += 256) {
        int vl = i & 7;
        int l = (i >> 3) % LIN;
        int c = i / (8 * LIN);
        sx[(c * 8 + vl) * LIN + l] = XM[(((size_t)n * 32 + c) * LIN + l) * 1000 + v0 + vl];
    }
    __syncthreads();
    int co = tid >> 3, vl = tid & 7;
    int s = co >> 3, co_s = co & 7;
    const int ksz[4] = {2, 3, 6, 7};
    int k = ksz[s];
    const float* fw = (s == 0) ? fw2 : ((s == 1) ? fw3 : ((s == 2) ? fw6 : fw7));
    const float* gw = (s == 0) ? gw2 : ((s == 1) ? gw3 : ((s == 2) ? gw6 : gw7));
    float accf[LOUT], accg[LOUT];
    float bf = fb[co], bg = gb[co];
#pragma unroll
    for (int l = 0; l < LOUT; ++l) { accf[l] = bf; accg[l] = bg; }
    for (int c = 0; c < 32; ++c) {
        const float* xp = &sx[(c * 8 + vl) * LIN];
        for (int j = 0; j < k; ++j) {
            float wf = fw[(co_s * 32 + c) * k + j];
            float wg = gw[(co_s * 32 + c) * k + j];
            int base = 7 - k + j;
#pragma unroll
            for (int l = 0; l < LOUT; ++l) {
                float xv = xp[base + l];
                accf[l] += wf * xv;
                accg[l] += wg * xv;
            }
        }
    }
    size_t ob = ((size_t)n * 32 + co) * LOUT * 1000 + v0 + vl;
    float lsum = 0.f, lss = 0.f;
    float swc = li0 ? sw_[co] : 0.f;
    float sbc = li0 ? sb_[co] : 0.f;
#pragma unroll
    for (int l = 0; l < LOUT; ++l) {
        float g = tanhf(accf[l]) * (1.f / (1.f + expf(-accg[l])));
        float r;
        if (li0)
            r = swc * g_inp[(n * 19 + l + 6) * 1000 + v0 + vl] + sbc;
        else
            r = Xp[(((size_t)n * 32 + co) * LIN + l + 6) * 1000 + v0 + vl];
        float y = g + r;
        XG[ob + (size_t)l * 1000] = y;
        sxg[(co * 8 + vl) * LOUT + l] = g;
        lsum += y;
        lss += y * y;
    }
    __syncthreads();
    int obk = tid >> 3;
    for (int half = 0; half < 2; ++half) {
        int o = obk + 32 * half;
        float acc = skb[o];
        for (int c = 0; c < 32; ++c) {
            const float* wp = &skw[((size_t)o * 32 + c) * LOUT];
            const float* xp = &sxg[(c * 8 + vl) * LOUT];
#pragma unroll
            for (int l = 0; l < LOUT; ++l) acc += wp[l] * xp[l];
        }
        size_t si = ((size_t)n * 64 + o) * 1000 + v0 + vl;
        g_skip[si] += acc;
    }
    // stats reduce: 64-lane shfl, then 4 wave partials, then 1 atomic pair
#pragma unroll
    for (int m = 1; m < 64; m <<= 1) {
        lsum += __shfl_xor(lsum, m);
        lss += __shfl_xor(lss, m);
    }
    int wvi = tid >> 6;
    if ((tid & 63) == 0) { ws1[wvi] = lsum; ws2[wvi] = lss; }
    __syncthreads();
    if (tid == 0) {
        float t1 = ws1[0] + ws1[1] + ws1[2] + ws1[3];
        float t2 = ws2[0] + ws2[1] + ws2[2] + ws2[3];
        atomicAdd(&stats[n * 2], t1);
        atomicAdd(&stats[n * 2 + 1], t2);
    }
}

__global__ void k_norm(int xnsel, const float* __restrict__ nw,
                       const float* __restrict__ nb, int li, int LOUT)
{
    float* XN = bufsel(xnsel);
    const float* stats = g_stats + li * 64;
    int S = 32 * LOUT * 1000;
    long long total = (long long)NBC * S;
    long long stride = (long long)gridDim.x * 256;
    for (long long i = (long long)blockIdx.x * 256 + threadIdx.x; i < total; i += stride) {
        int n = (int)(i / S);
        int rem = (int)(i % S);
        int v = rem % 1000;
        int l = (rem / 1000) % LOUT;
        int c = rem / (1000 * LOUT);
        int widx = (c * 1000 + v) * LOUT + l;
        float cnt = (float)S;
        float mu = stats[n * 2] / cnt;
        float var = stats[n * 2 + 1] / cnt - mu * mu;
        float rs = rsqrtf(var + EPS_C);
        XN[i] = (XN[i] - mu) * rs * nw[widx] + nb[widx];
    }
}

__global__ __launch_bounds__(256) void k_final(int xsel,
                                               const float* __restrict__ ew, const float* __restrict__ eb,
                                               const float* __restrict__ e1w, const float* __restrict__ e1b,
                                               const float* __restrict__ e2w, const float* __restrict__ e2b,
                                               float* __restrict__ out)
{
    const float* X = bufsel(xsel);
    __shared__ float sxf[32 * 16];
    __shared__ float sk[64 * 16];
    __shared__ float s1[64 * 16];
    __shared__ float s2[128 * 16];
    int b = blockIdx.y, v0 = blockIdx.x * 16;
    int tid = threadIdx.x;
    for (int i = tid; i < 512; i += 256) {
        int c = i / 16, vl = i & 15;
        int v = v0 + vl;
        sxf[i] = (v < 1000) ? X[((size_t)b * 32 + c) * 1000 + v] : 0.f;
    }
    for (int i = tid; i < 1024; i += 256) {
        int o = i / 16, vl = i & 15;
        int v = v0 + vl;
        sk[i] = (v < 1000) ? g_skip[((size_t)b * 64 + o) * 1000 + v] : 0.f;
    }
    __syncthreads();
    for (int i = tid; i < 1024; i += 256) {
        int o = i / 16, vl = i & 15;
        float acc = sk[i] + eb[o];
        for (int c = 0; c < 32; ++c) acc += ew[o * 32 + c] * sxf[c * 16 + vl];
        s1[i] = fmaxf(acc, 0.f);
    }
    __syncthreads();
    for (int i = tid; i < 2048; i += 256) {
        int o = i / 16, vl = i & 15;
        float acc = e1b[o];
        for (int c = 0; c < 64; ++c) acc += e1w[o * 64 + c] * s1[c * 16 + vl];
        s2[i] = fmaxf(acc, 0.f);
    }
    __syncthreads();
    if (tid < 192) {
        int o = tid / 16, vl = tid & 15;
        int v = v0 + vl;
        if (v < 1000) {
            float acc = e2b[o];
            for (int c = 0; c < 128; ++c) acc += e2w[o * 128 + c] * s2[c * 16 + vl];
            out[((size_t)b * 12 + o) * 1000 + v] = acc;
        }
    }
}

// ---------------- host ----------------

static const int SZ_SORT[43] = {240000,240000,128,8192,12,1536,96,1536,2304,4608,
                                5376,96,9216,96,9216,96,1536,2304,4608,5376,
                                480,19200,480,19200,416000,224000,32000,416000,224000,32000,
                                64,1216,64,2048,64,64,64,26624,14336,2048,32,32,768000};
static const int SZ_DICT[43] = {768000,32,32,1216,64,240000,240000,19200,480,19200,
                                480,9216,96,9216,96,1536,2304,4608,5376,96,
                                1536,2304,4608,5376,96,26624,64,416000,416000,14336,
                                64,224000,224000,2048,64,32000,32000,2048,64,8192,128,1536,12};
static const int SZ_SIG[43]  = {768000,32,32,1216,64,240000,240000,19200,480,19200,
                                480,9216,96,9216,96,1536,2304,4608,5376,96,
                                1536,2304,4608,5376,96,26624,64,14336,64,2048,
                                64,416000,416000,224000,224000,32000,32000,2048,64,8192,128,1536,12};

extern "C" void kernel_launch(void* const* d_in, const int* in_sizes, int n_in,
                              void* d_out, int out_size, void* d_ws, size_t ws_size,
                              hipStream_t stream)
{
    (void)d_ws; (void)ws_size;
    const float *x_in, *start_w, *start_b, *skip0_w, *skip0_b;
    const float *emb1, *emb2, *lin1_w, *lin1_b, *lin2_w, *lin2_b;
    const float *g1_w, *g1_b, *g2_w, *g2_b;
    const float *filt_w[4], *filt_b, *gate_w[4], *gate_b;
    const float *skw[3], *skb[3], *nww[3], *nbb[3];
    const float *skipE_w, *skipE_b, *end1_w, *end1_b, *end2_w, *end2_b;
    float* outp = (float*)d_out;
    auto P = [&](int i) { return (const float*)d_in[i]; };
    auto match = [&](const int* tab) {
        if (n_in < 43) return false;
        for (int i = 0; i < 43; ++i) if (in_sizes[i] != tab[i]) return false;
        return true;
    };

    int fam = -1;
    if (match(SZ_SORT)) fam = 0;
    else if (match(SZ_DICT)) fam = 1;
    else if (match(SZ_SIG)) fam = 2;

    if (fam == 0) {
        emb1 = P(0); emb2 = P(1); end1_b = P(2); end1_w = P(3); end2_b = P(4); end2_w = P(5);
        filt_b = P(6); filt_w[0] = P(7); filt_w[1] = P(8); filt_w[2] = P(9); filt_w[3] = P(10);
        g1_b = P(11); g1_w = P(12); g2_b = P(13); g2_w = P(14);
        gate_b = P(15); gate_w[0] = P(16); gate_w[1] = P(17); gate_w[2] = P(18); gate_w[3] = P(19);
        lin1_b = P(20); lin1_w = P(21); lin2_b = P(22); lin2_w = P(23);
        nbb[0] = P(24); nbb[1] = P(25); nbb[2] = P(26);
        nww[0] = P(27); nww[1] = P(28); nww[2] = P(29);
        skip0_b = P(30); skip0_w = P(31); skipE_b = P(32); skipE_w = P(33);
        skb[0] = P(34); skb[1] = P(35); skb[2] = P(36);
        skw[0] = P(37); skw[1] = P(38); skw[2] = P(39);
        start_b = P(40); start_w = P(41); x_in = P(42);
    } else if (fam == 1 || fam == 2) {
        x_in = P(0); start_w = P(1); start_b = P(2); skip0_w = P(3); skip0_b = P(4);
        emb1 = P(5); emb2 = P(6); lin1_w = P(7); lin1_b = P(8); lin2_w = P(9); lin2_b = P(10);
        g1_w = P(11); g1_b = P(12); g2_w = P(13); g2_b = P(14);
        filt_w[0] = P(15); filt_w[1] = P(16); filt_w[2] = P(17); filt_w[3] = P(18); filt_b = P(19);
        gate_w[0] = P(20); gate_w[1] = P(21); gate_w[2] = P(22); gate_w[3] = P(23); gate_b = P(24);
        if (fam == 1) {
            skw[0] = P(25); skb[0] = P(26); nww[0] = P(27); nbb[0] = P(28);
            skw[1] = P(29); skb[1] = P(30); nww[1] = P(31); nbb[1] = P(32);
            skw[2] = P(33); skb[2] = P(34); nww[2] = P(35); nbb[2] = P(36);
        } else {
            skw[0] = P(25); skb[0] = P(26); skw[1] = P(27); skb[1] = P(28);
            skw[2] = P(29); skb[2] = P(30);
            nww[0] = P(31); nbb[0] = P(32); nww[1] = P(33); nbb[1] = P(34);
            nww[2] = P(35); nbb[2] = P(36);
        }
        skipE_w = P(37); skipE_b = P(38); end1_w = P(39); end1_b = P(40);
        end2_w = P(41); end2_b = P(42);
    } else {
        k_out_zero<<<(out_size + 255) / 256, 256, 0, stream>>>(outp, out_size);
        k_marker<<<1, 64, 0, stream>>>(outp, 8192.0f);
        return;
    }

    // ---- setup ----
    k_init<<<12, 256, 0, stream>>>();
    k_build_inp<<<(32 * 19 * 1000 + 255) / 256, 256, 0, stream>>>(x_in);
    k_nv<<<(240000 + 255) / 256, 256, 0, stream>>>(emb1, emb2, lin1_w, lin1_b, lin2_w, lin2_b);
    k_adj_topk<<<3000, 256, 0, stream>>>();
    k_scan<<<3, 256, 0, stream>>>();
    k_permsort<<<3, 256, 0, stream>>>();
    k_scatter<<<(60000 + 255) / 256, 256, 0, stream>>>();
    k_packT1<<<(60000 + 255) / 256, 256, 0, stream>>>();
    k_packT2<<<12, 256, 0, stream>>>();

    // ---- full-batch pipeline (k_start folded into prop4/mix/incept li0) ----
    k_skip0<<<dim3(32, NBC), 256, 0, stream>>>(skip0_w, skip0_b);

    int X = 0;   // layer-0 "X buffer" is virtual (affine of g_inp)
    int LIN = 19;
    for (int li = 0; li < 3; ++li) {
        int LOUT = LIN - 6;
        int Pp = 1000 * LIN;
        int li0 = (li == 0) ? 1 : 0;
        int hb[4], hn = 0;
        for (int b = 0; b < 6 && hn < 4; ++b)
            if (b != X && b != 1) hb[hn++] = b;
        int h1 = hb[0], h2 = hb[1], h3 = hb[2], h4 = hb[3];
        int CH = 32 * LIN;
        dim3 gg((unsigned)(CH / 4), NBC);

        // all 4 hops in one launch: o1=P1, o2=P2, o3=Q1, o4=Q2
        k_prop4<<<gg, 256, 0, stream>>>(X, h1, h2, h3, h4, li, CH, li0, start_w, start_b);

        k_mix<<<dim3((Pp + 255) / 256, NBC), 256, 0, stream>>>(X, h1, h2, h3, h4, 1,
            g1_w + li * 3072, g2_w + li * 3072, g1_b + li * 32, g2_b + li * 32, Pp,
            li0, start_w, start_b);

        int XG = h1;
        if (LIN == 19)
            k_incept<19><<<dim3(125, NBC), 256, 0, stream>>>(1, XG, X,
                filt_w[0] + li * 512, filt_w[1] + li * 768, filt_w[2] + li * 1536, filt_w[3] + li * 1792,
                filt_b + li * 32,
                gate_w[0] + li * 512, gate_w[1] + li * 768, gate_w[2] + li * 1536, gate_w[3] + li * 1792,
                gate_b + li * 32, skw[li], skb[li], li, li0, start_w, start_b);
        else if (LIN == 13)
            k_incept<13><<<dim3(125, NBC), 256, 0, stream>>>(1, XG, X,
                filt_w[0] + li * 512, filt_w[1] + li * 768, filt_w[2] + li * 1536, filt_w[3] + li * 1792,
                filt_b + li * 32,
                gate_w[0] + li * 512, gate_w[1] + li * 768, gate_w[2] + li * 1536, gate_w[3] + li * 1792,
                gate_b + li * 32, skw[li], skb[li], li, li0, start_w, start_b);
        else
            k_incept<7><<<dim3(125, NBC), 256, 0, stream>>>(1, XG, X,
                filt_w[0] + li * 512, filt_w[1] + li * 768, filt_w[2] + li * 1536, filt_w[3] + li * 1792,
                filt_b + li * 32,
                gate_w[0] + li * 512, gate_w[1] + li * 768, gate_w[2] + li * 1536, gate_w[3] + li * 1792,
                gate_b + li * 32, skw[li], skb[li], li, li0, start_w, start_b);

        k_norm<<<2048, 256, 0, stream>>>(XG, nww[li], nbb[li], li, LOUT);

        X = XG;
        LIN = LOUT;
    }
    k_final<<<dim3(63, NBC), 256, 0, stream>>>(X, skipE_w, skipE_b,
                                               end1_w, end1_b, end2_w, end2_b, outp);
}

// Round 11
// 2565.499 us; speedup vs baseline: 1.0665x; 1.0203x over previous
//
#include <hip/hip_runtime.h>
#include <math.h>

// CoGNN forward. Round 40 (best = r39 2618us). prop4 DS-model: ~235us of
// 401 is ds_read (incl irreducible random-gather conflicts); rest is
// unhidden latency at 20 waves/CU (LDS-bound: 32KB -> 5 blocks x 4 waves).
// r37's 512-thr try failed ONLY because bounds(512,8) squeezed VGPR 48->32.
// This round: 512 threads with bounds(512,4) (VGPR cap 128 -> same ~48-reg
// body) -> 4 blocks x 8 waves = 32 waves/CU, half the per-CU edge-meta
// traffic, ILP unchanged. Tripwire: VGPR must stay ~48-64, hbm ~0.33GB.
// All r39 fusions kept (5-barrier prop4 with inline CSR stores + terminal
// Q2, incept+resid+stats fusion, li0 folding, shfl topk, float4 dots,
// pure powers, alpha folded into k_mix).
// B=32,C=32,V=1000,L:19->13->7->1. fp32.

#define ALPHA_C 0.05f
#define EPS_C 1e-5f
#define NBC 32
#define CSCT_CAP 140000

// ---------------- static device workspace ----------------
__device__ float g_inp[32 * 19 * 1000];
__device__ float g_skip[32 * 64 * 1000];
__device__ __align__(16) float g_nv1[240000];
__device__ __align__(16) float g_nv2[240000];
__device__ __align__(16) int   g_tkcol[60000];
__device__ __align__(16) float g_tkval[60000];
__device__ float g_inv1[3000];
__device__ int   g_colcnt[3000];
__device__ float g_colsum[3000];
__device__ int   g_rp2[3 * 1001 + 1];
__device__ int   g_fill[3000];
__device__ int   g_cscr[60000];
__device__ float g_cscv[60000];
__device__ float g_inv2[3000];
__device__ float g_stats[3 * 64];
__device__ __align__(16) int2 g_pk1T[60000];        // CSR transposed [li][j][v] = (col*16, w)
__device__ __align__(16) int2 g_cscT[3 * CSCT_CAP]; // CSC tiled-transposed (row*16, w)
__device__ int   g_perm[3 * 1024];   // [li][rank] -> v (global degree desc; -1 sentinel)
__device__ int   g_degT[3 * 1024];   // [li][rank] -> degree
__device__ int   g_iperm[3 * 1000];  // [li][v] -> rank
__device__ int   g_tOff[3 * 17];     // [li][tile] -> cscT base offset
__device__ float g_B0[(size_t)NBC * 32 * 19 * 1000];
__device__ float g_B1[(size_t)NBC * 32 * 19 * 1000];
__device__ float g_B2[(size_t)NBC * 32 * 19 * 1000];
__device__ float g_B3[(size_t)NBC * 32 * 19 * 1000];
__device__ float g_B4[(size_t)NBC * 32 * 19 * 1000];
__device__ float g_B5[(size_t)NBC * 32 * 19 * 1000];

__device__ __forceinline__ float* bufsel(int s)
{
    switch (s) {
        case 0: return g_B0;
        case 1: return g_B1;
        case 2: return g_B2;
        case 3: return g_B3;
        case 4: return g_B4;
        default: return g_B5;
    }
}

__global__ void k_init()
{
    int i = blockIdx.x * 256 + threadIdx.x;
    if (i < 3000) { g_colcnt[i] = 0; g_colsum[i] = 0.f; g_fill[i] = 0; }
    if (i < 192) g_stats[i] = 0.f;
}

__global__ void k_out_zero(float* __restrict__ out, int n)
{
    int i = blockIdx.x * 256 + threadIdx.x;
    if (i < n) out[i] = 0.0f;
}

__global__ void k_marker(float* __restrict__ out, float v)
{
    if (threadIdx.x == 0) out[0] = v;
}

// ---------------- setup ----------------

__global__ void k_build_inp(const float* __restrict__ xin)
{
    int i = blockIdx.x * 256 + threadIdx.x;
    if (i >= 32 * 19 * 1000) return;
    int v = i % 1000;
    int t = (i / 1000) % 19;
    int b = i / 19000;
    float val = 0.f;
    if (t >= 7) {
        int tt = t - 7;
        int n = (v < 500) ? v : v - 500;
        int f = (v < 500) ? 0 : 1;
        val = xin[((b * 12 + tt) * 500 + n) * 4 + f];
    }
    g_inp[i] = val;
}

__global__ void k_nv(const float* __restrict__ e1, const float* __restrict__ e2,
                     const float* __restrict__ w1, const float* __restrict__ b1,
                     const float* __restrict__ w2, const float* __restrict__ b2)
{
    int i = blockIdx.x * 256 + threadIdx.x;
    if (i >= 12 * 500 * 40) return;
    int o = i % 40;
    int n = (i / 40) % 500;
    int m = i / (40 * 500);
    const float4* p1 = (const float4*)(e1 + (m * 500 + n) * 40);
    const float4* pw1 = (const float4*)(w1 + (m * 40 + o) * 40);
    const float4* p2 = (const float4*)(e2 + (m * 500 + n) * 40);
    const float4* pw2 = (const float4*)(w2 + (m * 40 + o) * 40);
    float a1 = b1[m * 40 + o], a2 = b2[m * 40 + o];
    for (int d = 0; d < 10; ++d) {
        float4 x1 = p1[d], y1 = pw1[d];
        float4 x2 = p2[d], y2 = pw2[d];
        a1 += x1.x * y1.x; a1 += x1.y * y1.y; a1 += x1.z * y1.z; a1 += x1.w * y1.w;
        a2 += x2.x * y2.x; a2 += x2.y * y2.y; a2 += x2.z * y2.z; a2 += x2.w * y2.w;
    }
    g_nv1[i] = a1;
    g_nv2[i] = a2;
}

__global__ __launch_bounds__(256) void k_adj_topk()
{
    __shared__ float row[1000];
    __shared__ float wvv[4];
    __shared__ int wvi[4];
    __shared__ int selc[20];
    __shared__ float selv[20];
    int li = blockIdx.x / 1000;
    int r = blockIdx.x % 1000;
    int tid = threadIdx.x;
    int wv = tid >> 6, lane = tid & 63;
    int bi = r / 500, n = r % 500;
    for (int c = tid; c < 1000; c += 256) {
        int bj = c / 500, k = c % 500;
        int mg = li * 4 + 2 * bi + bj;
        const float4* a = (const float4*)(g_nv1 + (mg * 500 + n) * 40);
        const float4* b = (const float4*)(g_nv2 + (mg * 500 + k) * 40);
        float acc = 0.f;
#pragma unroll
        for (int d = 0; d < 10; ++d) {
            float4 av = a[d], bv = b[d];
            acc += av.x * bv.x; acc += av.y * bv.y;
            acc += av.z * bv.z; acc += av.w * bv.w;
        }
        row[c] = acc;
    }
    __syncthreads();
    for (int sel = 0; sel < 20; ++sel) {
        float bv = -INFINITY;
        int bidx = 0;
        for (int c = tid; c < 1000; c += 256) {
            float x = row[c];
            if (x > bv) { bv = x; bidx = c; }
        }
#pragma unroll
        for (int m = 1; m < 64; m <<= 1) {
            float ov = __shfl_xor(bv, m);
            int oi = __shfl_xor(bidx, m);
            if (ov > bv || (ov == bv && oi < bidx)) { bv = ov; bidx = oi; }
        }
        if (lane == 0) { wvv[wv] = bv; wvi[wv] = bidx; }
        __syncthreads();
        if (tid == 0) {
            float fv = wvv[0];
            int fi = wvi[0];
#pragma unroll
            for (int k = 1; k < 4; ++k) {
                float ov = wvv[k];
                int oi = wvi[k];
                if (ov > fv || (ov == fv && oi < fi)) { fv = ov; fi = oi; }
            }
            int ci = fi;
            if (ci < 0 || ci > 999) ci = sel;
            selc[sel] = ci;
            selv[sel] = fv;
            g_tkcol[(li * 1000 + r) * 20 + sel] = ci;
            g_tkval[(li * 1000 + r) * 20 + sel] = fv;
            row[ci] = -INFINITY;
        }
        __syncthreads();
    }
    if (tid < 20) {
        atomicAdd(&g_colcnt[li * 1000 + selc[tid]], 1);
        atomicAdd(&g_colsum[li * 1000 + selc[tid]], selv[tid]);
    }
    if (tid == 0) {
        float s = 0.f;
        for (int j = 0; j < 20; ++j) s += selv[j];
        g_inv1[li * 1000 + r] = 1.f / (s + 1.f);
    }
}

__global__ __launch_bounds__(256) void k_scan()
{
    __shared__ int s[1000];
    int li = blockIdx.x;
    int tid = threadIdx.x;
    for (int i = tid; i < 1000; i += 256) s[i] = g_colcnt[li * 1000 + i];
    __syncthreads();
    if (tid == 0) {
        int run = 0;
        for (int i = 0; i < 1000; ++i) { int c = s[i]; s[i] = run; run += c; }
        g_rp2[li * 1001 + 1000] = run;
    }
    __syncthreads();
    for (int i = tid; i < 1000; i += 256) {
        g_rp2[li * 1001 + i] = s[i];
        g_inv2[li * 1000 + i] = 1.f / (g_colsum[li * 1000 + i] + 1.f);
    }
}

// global exact degree rank sort (desc, ties by index) + tile offsets
__global__ __launch_bounds__(256) void k_permsort()
{
    __shared__ int deg[1000];
    __shared__ int tmax[16];
    int li = blockIdx.x;
    int tid = threadIdx.x;
    for (int v = tid; v < 1000; v += 256)
        deg[v] = g_rp2[li * 1001 + v + 1] - g_rp2[li * 1001 + v];
    __syncthreads();
    for (int v = tid; v < 1000; v += 256) {
        int d = deg[v];
        int r = 0;
        for (int u = 0; u < 1000; ++u) {
            int du = deg[u];
            r += (du > d) || (du == d && u < v);
        }
        g_perm[li * 1024 + r] = v;
        g_degT[li * 1024 + r] = d;
        g_iperm[li * 1000 + v] = r;
        if ((r & 63) == 0) tmax[r >> 6] = d;
    }
    if (tid < 24) {
        g_perm[li * 1024 + 1000 + tid] = -1;
        g_degT[li * 1024 + 1000 + tid] = 0;
    }
    __syncthreads();
    if (tid == 0) {
        int off = 0;
        for (int t = 0; t < 16; ++t) {
            g_tOff[li * 17 + t] = off;
            off += 64 * tmax[t];
        }
        g_tOff[li * 17 + 16] = off;
    }
}

__global__ void k_scatter()
{
    int i = blockIdx.x * 256 + threadIdx.x;
    if (i >= 3 * 20000) return;
    int li = i / 20000;
    int e = i % 20000;
    int r = e / 20;
    int c = g_tkcol[i];
    if (c < 0) c = 0;
    if (c > 999) c = 999;
    float v = g_tkval[i];
    int pos = g_rp2[li * 1001 + c] + atomicAdd(&g_fill[li * 1000 + c], 1);
    if (pos < 0) pos = 0;
    if (pos > 19999) pos = 19999;
    g_cscr[li * 20000 + pos] = r;
    g_cscv[li * 20000 + pos] = v;
}

// transposed CSR pack: pk1T[li][j][v] = (col*16, w)  (byte-premult for float4)
__global__ void k_packT1()
{
    int i = blockIdx.x * 256 + threadIdx.x;
    if (i >= 60000) return;
    int li = i / 20000;
    int e = i % 20000;
    int v = e / 20, j = e % 20;
    int c1 = g_tkcol[i];
    if (c1 < 0) c1 = 0;
    if (c1 > 999) c1 = 999;
    g_pk1T[li * 20000 + j * 1000 + v] = make_int2(c1 * 16, __float_as_int(g_tkval[i]));
}

// tiled-transposed CSC pack: cscT[tOff[t] + j*64 + lane] = (row*16, w)
__global__ void k_packT2()
{
    int i = blockIdx.x * 256 + threadIdx.x;
    if (i >= 3000) return;
    int li = i / 1000, v = i % 1000;
    int r = g_iperm[li * 1000 + v];
    int t = r >> 6, ln = r & 63;
    int j0 = g_rp2[li * 1001 + v];
    int d = g_rp2[li * 1001 + v + 1] - j0;
    int base = g_tOff[li * 17 + t];
    for (int j = 0; j < d; ++j) {
        int row = g_cscr[li * 20000 + j0 + j];
        if (row < 0) row = 0;
        if (row > 999) row = 999;
        int pos = base + j * 64 + ln;
        if (pos >= 0 && pos < CSCT_CAP)
            g_cscT[li * CSCT_CAP + pos] =
                make_int2(row * 16, __float_as_int(g_cscv[li * 20000 + j0 + j]));
    }
}

// ---------------- pipeline kernels ([n][ch][v] layout, ch = c*L + l) ----------------

__global__ __launch_bounds__(256) void k_skip0(const float* __restrict__ w,
                                               const float* __restrict__ bb)
{
    __shared__ float s_inp[19 * 32];
    __shared__ float s_w[64 * 19];
    int b = blockIdx.y;
    int v0 = blockIdx.x * 32;
    int tid = threadIdx.x;
    for (int i = tid; i < 64 * 19; i += 256) s_w[i] = w[i];
    for (int i = tid; i < 19 * 32; i += 256) {
        int t = i / 32, vl = i % 32;
        int v = v0 + vl;
        s_inp[i] = (v < 1000) ? g_inp[(b * 19 + t) * 1000 + v] : 0.f;
    }
    __syncthreads();
    for (int e = tid; e < 64 * 32; e += 256) {
        int o = e / 32, vl = e % 32;
        int v = v0 + vl;
        if (v >= 1000) continue;
        float acc = bb[o];
#pragma unroll
        for (int t = 0; t < 19; ++t) acc += s_w[o * 19 + t] * s_inp[t * 32 + vl];
        g_skip[(b * 64 + o) * 1000 + v] = acc;
    }
}

// All 4 mixprop hops, one launch, CH_BLK=4 channels per block (float4/col),
// 512-thread blocks with bounds(512,4): VGPR cap 128 -> compiler keeps the
// ~48-reg body (r37's (512,8) squeezed it to 32 = regression), 4 blocks x
// 8 waves = 32 waves/CU, half the per-CU edge-meta traffic.
// Pass-reduced schedule (P2/Q2 terminal, X stays in U):
//  1 stage X->U | 2 P1=csr(U)->W + inline store | 3 P2=csr(W) store-only |
//  4 Q1=csc(U)->W | 5 store o3 from W + Q2=csc(W)->U | 6 store o4 from U.
__global__ __launch_bounds__(512, 4) void k_prop4(int xsel, int o1s, int o2s, int o3s, int o4s,
                                                  int li, int CH, int li0,
                                                  const float* __restrict__ sw,
                                                  const float* __restrict__ sb)
{
    __shared__ float4 S[2000];   // U = S[0..999], W = S[1000..1999]
    const float* X = bufsel(xsel);
    float* o1 = bufsel(o1s);
    float* o2 = bufsel(o2s);
    float* o3 = bufsel(o3s);
    float* o4 = bufsel(o4s);
    const int2* pkT = g_pk1T + li * 20000;
    const int2* cT = g_cscT + (size_t)li * CSCT_CAP;
    const int* prm = g_perm + li * 1024;
    const int* dgT = g_degT + li * 1024;
    const int* tOf = g_tOff + li * 17;
    const float* iv1 = g_inv1 + li * 1000;
    const float* iv2 = g_inv2 + li * 1000;
    int n = blockIdx.y;
    int ch0 = blockIdx.x * 4;
    size_t gb = ((size_t)n * CH + ch0) * 1000;
    int tid = threadIdx.x;
    int wv = tid >> 6, lane = tid & 63;
    char* Ub = (char*)S;
    char* Wb = (char*)(S + 1000);
    float4* U4 = S;
    float4* W4 = S + 1000;

    // CSR hop: res[v] = (src[v] + sum_j w_j src[col_j]) * iv1[v];
    // optional LDS write (dst) + inline coalesced global store (gout).
    auto csr_hop = [&](const char* sbuf, float4* dst, float* gout) {
        for (int it = 0; it < 2; ++it) {
            int v = it * 512 + tid;
            if (v >= 1000) break;
            const int2* mp = pkT + v;
            float4 a = *(const float4*)(sbuf + (size_t)v * 16);
#pragma unroll
            for (int jb = 0; jb < 5; ++jb) {
                int2 e0 = mp[(jb * 4 + 0) * 1000];
                int2 e1 = mp[(jb * 4 + 1) * 1000];
                int2 e2 = mp[(jb * 4 + 2) * 1000];
                int2 e3 = mp[(jb * 4 + 3) * 1000];
                float w0 = __int_as_float(e0.y), w1 = __int_as_float(e1.y);
                float w2 = __int_as_float(e2.y), w3 = __int_as_float(e3.y);
                float4 x0 = *(const float4*)(sbuf + e0.x);
                float4 x1 = *(const float4*)(sbuf + e1.x);
                float4 x2 = *(const float4*)(sbuf + e2.x);
                float4 x3 = *(const float4*)(sbuf + e3.x);
                a.x += w0 * x0.x + w1 * x1.x + w2 * x2.x + w3 * x3.x;
                a.y += w0 * x0.y + w1 * x1.y + w2 * x2.y + w3 * x3.y;
                a.z += w0 * x0.z + w1 * x1.z + w2 * x2.z + w3 * x3.z;
                a.w += w0 * x0.w + w1 * x1.w + w2 * x2.w + w3 * x3.w;
            }
            float s = iv1[v];
            a.x *= s; a.y *= s; a.z *= s; a.w *= s;
            if (dst) dst[v] = a;
            gout[gb + v] = a.x;
            gout[gb + 1000 + v] = a.y;
            gout[gb + 2000 + v] = a.z;
            gout[gb + 3000 + v] = a.w;
        }
    };

    // CSC hop: dst[v] = (src[v] + sum_j w_j src[row_j]) * iv2[v] (scattered)
    auto csc_hop = [&](const char* sbuf, float4* dst) {
        for (int o = 0; o < 2; ++o) {
            int tile = o * 8 + ((o & 1) ? (7 - wv) : wv);   // snake balance
            int r = tile * 64 + lane;
            int v = prm[r];
            if (v < 0) continue;
            int d = dgT[r];
            const int2* mp = cT + tOf[tile] + lane;
            float4 a = *(const float4*)(sbuf + (size_t)v * 16);
            int j = 0;
            for (; j + 4 <= d; j += 4) {
                int2 e0 = mp[(j + 0) * 64];
                int2 e1 = mp[(j + 1) * 64];
                int2 e2 = mp[(j + 2) * 64];
                int2 e3 = mp[(j + 3) * 64];
                float w0 = __int_as_float(e0.y), w1 = __int_as_float(e1.y);
                float w2 = __int_as_float(e2.y), w3 = __int_as_float(e3.y);
                float4 x0 = *(const float4*)(sbuf + e0.x);
                float4 x1 = *(const float4*)(sbuf + e1.x);
                float4 x2 = *(const float4*)(sbuf + e2.x);
                float4 x3 = *(const float4*)(sbuf + e3.x);
                a.x += w0 * x0.x + w1 * x1.x + w2 * x2.x + w3 * x3.x;
                a.y += w0 * x0.y + w1 * x1.y + w2 * x2.y + w3 * x3.y;
                a.z += w0 * x0.z + w1 * x1.z + w2 * x2.z + w3 * x3.z;
                a.w += w0 * x0.w + w1 * x1.w + w2 * x2.w + w3 * x3.w;
            }
            for (; j < d; ++j) {
                int2 e = mp[j * 64];
                float w = __int_as_float(e.y);
                float4 x = *(const float4*)(sbuf + e.x);
                a.x += w * x.x; a.y += w * x.y; a.z += w * x.z; a.w += w * x.w;
            }
            float s = iv2[v];
            a.x *= s; a.y *= s; a.z *= s; a.w *= s;
            dst[v] = a;
        }
    };

    // phase 1: stage X -> U (li0: affine of g_inp, else global read)
    if (li0) {
        float swv0 = sw[(ch0 + 0) / 19], sbv0 = sb[(ch0 + 0) / 19];
        float swv1 = sw[(ch0 + 1) / 19], sbv1 = sb[(ch0 + 1) / 19];
        float swv2 = sw[(ch0 + 2) / 19], sbv2 = sb[(ch0 + 2) / 19];
        float swv3 = sw[(ch0 + 3) / 19], sbv3 = sb[(ch0 + 3) / 19];
        const float* i0 = g_inp + (n * 19 + (ch0 + 0) % 19) * 1000;
        const float* i1 = g_inp + (n * 19 + (ch0 + 1) % 19) * 1000;
        const float* i2 = g_inp + (n * 19 + (ch0 + 2) % 19) * 1000;
        const float* i3 = g_inp + (n * 19 + (ch0 + 3) % 19) * 1000;
        for (int it = 0; it < 2; ++it) {
            int v = it * 512 + tid;
            if (v >= 1000) break;
            float4 t;
            t.x = swv0 * i0[v] + sbv0;
            t.y = swv1 * i1[v] + sbv1;
            t.z = swv2 * i2[v] + sbv2;
            t.w = swv3 * i3[v] + sbv3;
            U4[v] = t;
        }
    } else {
        for (int it = 0; it < 2; ++it) {
            int v = it * 512 + tid;
            if (v >= 1000) break;
            float4 t;
            t.x = X[gb + v];
            t.y = X[gb + 1000 + v];
            t.z = X[gb + 2000 + v];
            t.w = X[gb + 3000 + v];
            U4[v] = t;
        }
    }
    __syncthreads();

    // phase 2: P1 = CSR(U) -> W + inline store o1
    csr_hop(Ub, W4, o1);
    __syncthreads();

    // phase 3: P2 = CSR(W) -> store o2 only (terminal; U=X preserved)
    csr_hop(Wb, (float4*)nullptr, o2);
    __syncthreads();

    // phase 4: Q1 = CSC(U) -> W (scattered; overwrites P1 after sync)
    csc_hop(Ub, W4);
    __syncthreads();

    // phase 5: coalesced store o3 from W; Q2 = CSC(W) -> U (terminal in LDS)
    for (int it = 0; it < 2; ++it) {
        int v = it * 512 + tid;
        if (v >= 1000) break;
        float4 t = W4[v];
        o3[gb + v] = t.x;
        o3[gb + 1000 + v] = t.y;
        o3[gb + 2000 + v] = t.z;
        o3[gb + 3000 + v] = t.w;
    }
    csc_hop(Wb, U4);
    __syncthreads();

    // phase 6: coalesced store o4 from U
    for (int it = 0; it < 2; ++it) {
        int v = it * 512 + tid;
        if (v >= 1000) break;
        float4 t = U4[v];
        o4[gb + v] = t.x;
        o4[gb + 1000 + v] = t.y;
        o4[gb + 2000 + v] = t.z;
        o4[gb + 3000 + v] = t.w;
    }
}

// srcs are {X, P1=Mx, P2=M^2x, Q1=M'x, Q2=M'^2x}; alpha-mix folded into
// the weights (exact): with b=1-a,
//   wx' = wx + a*(w1+w2+w3+w4); wP1 = b*(w1+a*w2); wP2 = b^2*w2;
//   wQ1 = b*(w3+a*w4); wQ2 = b^2*w4.
// li0: X = sw[c]*inp+sb[c] broadcast -> st0 collapses to
//   inp[l][v]*sum_c(wx'[o][c]sw[c]) + sum_c(wx'[o][c]sb[c]).
__global__ __launch_bounds__(256) void k_mix(int xs, int h1s, int h2s, int h3s, int h4s, int ms,
                                             const float* __restrict__ g1w, const float* __restrict__ g2w,
                                             const float* __restrict__ g1b, const float* __restrict__ g2b,
                                             int P, int li0,
                                             const float* __restrict__ sw_,
                                             const float* __restrict__ sb_)
{
    __shared__ float sW[5 * 1024];
    __shared__ float sB[32];
    __shared__ float sWS[32];
    __shared__ float sSB[32];
    int tid = threadIdx.x;
    const float A = ALPHA_C, Bq = 1.f - ALPHA_C;
    for (int i = tid; i < 1024; i += 256) {
        int o = i >> 5, c = i & 31;
        float w1 = g1w[o * 96 + 32 + c], w2 = g1w[o * 96 + 64 + c];
        float w3 = g2w[o * 96 + 32 + c], w4 = g2w[o * 96 + 64 + c];
        sW[i]        = g1w[o * 96 + c] + g2w[o * 96 + c] + A * (w1 + w2 + w3 + w4);
        sW[1024 + i] = Bq * (w1 + A * w2);
        sW[2048 + i] = Bq * Bq * w2;
        sW[3072 + i] = Bq * (w3 + A * w4);
        sW[4096 + i] = Bq * Bq * w4;
    }
    if (tid < 32) sB[tid] = g1b[tid] + g2b[tid];
    __syncthreads();
    if (li0 && tid < 32) {
        float as = 0.f, ab = 0.f;
        for (int c = 0; c < 32; ++c) {
            float w = sW[tid * 32 + c];
            as += w * sw_[c];
            ab += w * sb_[c];
        }
        sWS[tid] = as;
        sSB[tid] = ab;
    }
    if (li0) __syncthreads();
    int n = blockIdx.y;
    int p = blockIdx.x * 256 + tid;
    if (p >= P) return;
    const float* srcs[5] = {bufsel(xs), bufsel(h1s), bufsel(h2s), bufsel(h3s), bufsel(h4s)};
    float acc[32];
    int st0;
    if (li0) {
        float xv = g_inp[(size_t)n * 19000 + p];
#pragma unroll
        for (int o = 0; o < 32; ++o) acc[o] = sB[o] + sSB[o] + sWS[o] * xv;
        st0 = 1;
    } else {
#pragma unroll
        for (int o = 0; o < 32; ++o) acc[o] = sB[o];
        st0 = 0;
    }
    for (int st = st0; st < 5; ++st) {
        const float* src = srcs[st] + (size_t)n * 32 * P + p;
        const float* w = &sW[st * 1024];
        for (int c = 0; c < 32; ++c) {
            float hv = src[(size_t)c * P];
#pragma unroll
            for (int o = 0; o < 32; ++o) acc[o] += w[o * 32 + c] * hv;
        }
    }
    float* XM = bufsel(ms) + (size_t)n * 32 * P + p;
#pragma unroll
    for (int o = 0; o < 32; ++o) XM[(size_t)o * P] = acc[o];
}

// inception + tanh*sigmoid + fused skip-conv + FUSED residual & layernorm
// stats (sum/sumsq via shfl reduce + 2 atomics/block). Skip conv uses the
// pre-residual gated value (reference semantics); XG receives y = g + resid.
template <int LIN>
__global__ __launch_bounds__(256) void k_incept(int xmsel, int xgsel, int xpsel,
                                                const float* __restrict__ fw2, const float* __restrict__ fw3,
                                                const float* __restrict__ fw6, const float* __restrict__ fw7,
                                                const float* __restrict__ fb,
                                                const float* __restrict__ gw2, const float* __restrict__ gw3,
                                                const float* __restrict__ gw6, const float* __restrict__ gw7,
                                                const float* __restrict__ gb,
                                                const float* __restrict__ skw, const float* __restrict__ skb,
                                                int li, int li0,
                                                const float* __restrict__ sw_,
                                                const float* __restrict__ sb_)
{
    const int LOUT = LIN - 6;
    const float* XM = bufsel(xmsel);
    float* XG = bufsel(xgsel);
    const float* Xp = bufsel(xpsel);
    float* stats = g_stats + li * 64;
    __shared__ float sx[32 * 8 * LIN];
    __shared__ float sxg[32 * 8 * LOUT];
    __shared__ float ws1[4], ws2[4];
    int tid = threadIdx.x;
    int n = blockIdx.y, v0 = blockIdx.x * 8;
    for (int i = tid; i < 32 * LIN * 8; i += 256) {
        int vl = i & 7;
        int l = (i >> 3) % LIN;
        int c = i / (8 * LIN);
        sx[(c * 8 + vl) * LIN + l] = XM[(((size_t)n * 32 + c) * LIN + l) * 1000 + v0 + vl];
    }
    __syncthreads();
    int co = tid >> 3, vl = tid & 7;
    int s = co >> 3, co_s = co & 7;
    const int ksz[4] = {2, 3, 6, 7};
    int k = ksz[s];
    const float* fw = (s == 0) ? fw2 : ((s == 1) ? fw3 : ((s == 2) ? fw6 : fw7));
    const float* gw = (s == 0) ? gw2 : ((s == 1) ? gw3 : ((s == 2) ? gw6 : gw7));
    float accf[LOUT], accg[LOUT];
    float bf = fb[co], bg = gb[co];
#pragma unroll
    for (int l = 0; l < LOUT; ++l) { accf[l] = bf; accg[l] = bg; }
    for (int c = 0; c < 32; ++c) {
        const float* xp = &sx[(c * 8 + vl) * LIN];
        for (int j = 0; j < k; ++j) {
            float wf = fw[(co_s * 32 + c) * k + j];
            float wg = gw[(co_s * 32 + c) * k + j];
            int base = 7 - k + j;
#pragma unroll
            for (int l = 0; l < LOUT; ++l) {
                float xv = xp[base + l];
                accf[l] += wf * xv;
                accg[l] += wg * xv;
            }
        }
    }
    size_t ob = ((size_t)n * 32 + co) * LOUT * 1000 + v0 + vl;
    float lsum = 0.f, lss = 0.f;
    float swc = li0 ? sw_[co] : 0.f;
    float sbc = li0 ? sb_[co] : 0.f;
#pragma unroll
    for (int l = 0; l < LOUT; ++l) {
        float g = tanhf(accf[l]) * (1.f / (1.f + expf(-accg[l])));
        float r;
        if (li0)
            r = swc * g_inp[(n * 19 + l + 6) * 1000 + v0 + vl] + sbc;
        else
            r = Xp[(((size_t)n * 32 + co) * LIN + l + 6) * 1000 + v0 + vl];
        float y = g + r;
        XG[ob + (size_t)l * 1000] = y;
        sxg[(co * 8 + vl) * LOUT + l] = g;
        lsum += y;
        lss += y * y;
    }
    __syncthreads();
    int obk = tid >> 3;
    for (int half = 0; half < 2; ++half) {
        int o = obk + 32 * half;
        float acc = skb[o];
        for (int c = 0; c < 32; ++c) {
            const float* wp = &skw[((size_t)o * 32 + c) * LOUT];
            const float* xp = &sxg[(c * 8 + vl) * LOUT];
#pragma unroll
            for (int l = 0; l < LOUT; ++l) acc += wp[l] * xp[l];
        }
        size_t si = ((size_t)n * 64 + o) * 1000 + v0 + vl;
        g_skip[si] += acc;
    }
    // stats reduce: 64-lane shfl, then 4 wave partials, then 1 atomic pair
#pragma unroll
    for (int m = 1; m < 64; m <<= 1) {
        lsum += __shfl_xor(lsum, m);
        lss += __shfl_xor(lss, m);
    }
    int wvi = tid >> 6;
    if ((tid & 63) == 0) { ws1[wvi] = lsum; ws2[wvi] = lss; }
    __syncthreads();
    if (tid == 0) {
        float t1 = ws1[0] + ws1[1] + ws1[2] + ws1[3];
        float t2 = ws2[0] + ws2[1] + ws2[2] + ws2[3];
        atomicAdd(&stats[n * 2], t1);
        atomicAdd(&stats[n * 2 + 1], t2);
    }
}

__global__ void k_norm(int xnsel, const float* __restrict__ nw,
                       const float* __restrict__ nb, int li, int LOUT)
{
    float* XN = bufsel(xnsel);
    const float* stats = g_stats + li * 64;
    int S = 32 * LOUT * 1000;
    long long total = (long long)NBC * S;
    long long stride = (long long)gridDim.x * 256;
    for (long long i = (long long)blockIdx.x * 256 + threadIdx.x; i < total; i += stride) {
        int n = (int)(i / S);
        int rem = (int)(i % S);
        int v = rem % 1000;
        int l = (rem / 1000) % LOUT;
        int c = rem / (1000 * LOUT);
        int widx = (c * 1000 + v) * LOUT + l;
        float cnt = (float)S;
        float mu = stats[n * 2] / cnt;
        float var = stats[n * 2 + 1] / cnt - mu * mu;
        float rs = rsqrtf(var + EPS_C);
        XN[i] = (XN[i] - mu) * rs * nw[widx] + nb[widx];
    }
}

__global__ __launch_bounds__(256) void k_final(int xsel,
                                               const float* __restrict__ ew, const float* __restrict__ eb,
                                               const float* __restrict__ e1w, const float* __restrict__ e1b,
                                               const float* __restrict__ e2w, const float* __restrict__ e2b,
                                               float* __restrict__ out)
{
    const float* X = bufsel(xsel);
    __shared__ float sxf[32 * 16];
    __shared__ float sk[64 * 16];
    __shared__ float s1[64 * 16];
    __shared__ float s2[128 * 16];
    int b = blockIdx.y, v0 = blockIdx.x * 16;
    int tid = threadIdx.x;
    for (int i = tid; i < 512; i += 256) {
        int c = i / 16, vl = i & 15;
        int v = v0 + vl;
        sxf[i] = (v < 1000) ? X[((size_t)b * 32 + c) * 1000 + v] : 0.f;
    }
    for (int i = tid; i < 1024; i += 256) {
        int o = i / 16, vl = i & 15;
        int v = v0 + vl;
        sk[i] = (v < 1000) ? g_skip[((size_t)b * 64 + o) * 1000 + v] : 0.f;
    }
    __syncthreads();
    for (int i = tid; i < 1024; i += 256) {
        int o = i / 16, vl = i & 15;
        float acc = sk[i] + eb[o];
        for (int c = 0; c < 32; ++c) acc += ew[o * 32 + c] * sxf[c * 16 + vl];
        s1[i] = fmaxf(acc, 0.f);
    }
    __syncthreads();
    for (int i = tid; i < 2048; i += 256) {
        int o = i / 16, vl = i & 15;
        float acc = e1b[o];
        for (int c = 0; c < 64; ++c) acc += e1w[o * 64 + c] * s1[c * 16 + vl];
        s2[i] = fmaxf(acc, 0.f);
    }
    __syncthreads();
    if (tid < 192) {
        int o = tid / 16, vl = tid & 15;
        int v = v0 + vl;
        if (v < 1000) {
            float acc = e2b[o];
            for (int c = 0; c < 128; ++c) acc += e2w[o * 128 + c] * s2[c * 16 + vl];
            out[((size_t)b * 12 + o) * 1000 + v] = acc;
        }
    }
}

// ---------------- host ----------------

static const int SZ_SORT[43] = {240000,240000,128,8192,12,1536,96,1536,2304,4608,
                                5376,96,9216,96,9216,96,1536,2304,4608,5376,
                                480,19200,480,19200,416000,224000,32000,416000,224000,32000,
                                64,1216,64,2048,64,64,64,26624,14336,2048,32,32,768000};
static const int SZ_DICT[43] = {768000,32,32,1216,64,240000,240000,19200,480,19200,
                                480,9216,96,9216,96,1536,2304,4608,5376,96,
                                1536,2304,4608,5376,96,26624,64,416000,416000,14336,
                                64,224000,224000,2048,64,32000,32000,2048,64,8192,128,1536,12};
static const int SZ_SIG[43]  = {768000,32,32,1216,64,240000,240000,19200,480,19200,
                                480,9216,96,9216,96,1536,2304,4608,5376,96,
                                1536,2304,4608,5376,96,26624,64,14336,64,2048,
                                64,416000,416000,224000,224000,32000,32000,2048,64,8192,128,1536,12};

extern "C" void kernel_launch(void* const* d_in, const int* in_sizes, int n_in,
                              void* d_out, int out_size, void* d_ws, size_t ws_size,
                              hipStream_t stream)
{
    (void)d_ws; (void)ws_size;
    const float *x_in, *start_w, *start_b, *skip0_w, *skip0_b;
    const float *emb1, *emb2, *lin1_w, *lin1_b, *lin2_w, *lin2_b;
    const float *g1_w, *g1_b, *g2_w, *g2_b;
    const float *filt_w[4], *filt_b, *gate_w[4], *gate_b;
    const float *skw[3], *skb[3], *nww[3], *nbb[3];
    const float *skipE_w, *skipE_b, *end1_w, *end1_b, *end2_w, *end2_b;
    float* outp = (float*)d_out;
    auto P = [&](int i) { return (const float*)d_in[i]; };
    auto match = [&](const int* tab) {
        if (n_in < 43) return false;
        for (int i = 0; i < 43; ++i) if (in_sizes[i] != tab[i]) return false;
        return true;
    };

    int fam = -1;
    if (match(SZ_SORT)) fam = 0;
    else if (match(SZ_DICT)) fam = 1;
    else if (match(SZ_SIG)) fam = 2;

    if (fam == 0) {
        emb1 = P(0); emb2 = P(1); end1_b = P(2); end1_w = P(3); end2_b = P(4); end2_w = P(5);
        filt_b = P(6); filt_w[0] = P(7); filt_w[1] = P(8); filt_w[2] = P(9); filt_w[3] = P(10);
        g1_b = P(11); g1_w = P(12); g2_b = P(13); g2_w = P(14);
        gate_b = P(15); gate_w[0] = P(16); gate_w[1] = P(17); gate_w[2] = P(18); gate_w[3] = P(19);
        lin1_b = P(20); lin1_w = P(21); lin2_b = P(22); lin2_w = P(23);
        nbb[0] = P(24); nbb[1] = P(25); nbb[2] = P(26);
        nww[0] = P(27); nww[1] = P(28); nww[2] = P(29);
        skip0_b = P(30); skip0_w = P(31); skipE_b = P(32); skipE_w = P(33);
        skb[0] = P(34); skb[1] = P(35); skb[2] = P(36);
        skw[0] = P(37); skw[1] = P(38); skw[2] = P(39);
        start_b = P(40); start_w = P(41); x_in = P(42);
    } else if (fam == 1 || fam == 2) {
        x_in = P(0); start_w = P(1); start_b = P(2); skip0_w = P(3); skip0_b = P(4);
        emb1 = P(5); emb2 = P(6); lin1_w = P(7); lin1_b = P(8); lin2_w = P(9); lin2_b = P(10);
        g1_w = P(11); g1_b = P(12); g2_w = P(13); g2_b = P(14);
        filt_w[0] = P(15); filt_w[1] = P(16); filt_w[2] = P(17); filt_w[3] = P(18); filt_b = P(19);
        gate_w[0] = P(20); gate_w[1] = P(21); gate_w[2] = P(22); gate_w[3] = P(23); gate_b = P(24);
        if (fam == 1) {
            skw[0] = P(25); skb[0] = P(26); nww[0] = P(27); nbb[0] = P(28);
            skw[1] = P(29); skb[1] = P(30); nww[1] = P(31); nbb[1] = P(32);
            skw[2] = P(33); skb[2] = P(34); nww[2] = P(35); nbb[2] = P(36);
        } else {
            skw[0] = P(25); skb[0] = P(26); skw[1] = P(27); skb[1] = P(28);
            skw[2] = P(29); skb[2] = P(30);
            nww[0] = P(31); nbb[0] = P(32); nww[1] = P(33); nbb[1] = P(34);
            nww[2] = P(35); nbb[2] = P(36);
        }
        skipE_w = P(37); skipE_b = P(38); end1_w = P(39); end1_b = P(40);
        end2_w = P(41); end2_b = P(42);
    } else {
        k_out_zero<<<(out_size + 255) / 256, 256, 0, stream>>>(outp, out_size);
        k_marker<<<1, 64, 0, stream>>>(outp, 8192.0f);
        return;
    }

    // ---- setup ----
    k_init<<<12, 256, 0, stream>>>();
    k_build_inp<<<(32 * 19 * 1000 + 255) / 256, 256, 0, stream>>>(x_in);
    k_nv<<<(240000 + 255) / 256, 256, 0, stream>>>(emb1, emb2, lin1_w, lin1_b, lin2_w, lin2_b);
    k_adj_topk<<<3000, 256, 0, stream>>>();
    k_scan<<<3, 256, 0, stream>>>();
    k_permsort<<<3, 256, 0, stream>>>();
    k_scatter<<<(60000 + 255) / 256, 256, 0, stream>>>();
    k_packT1<<<(60000 + 255) / 256, 256, 0, stream>>>();
    k_packT2<<<12, 256, 0, stream>>>();

    // ---- full-batch pipeline (k_start folded into prop4/mix/incept li0) ----
    k_skip0<<<dim3(32, NBC), 256, 0, stream>>>(skip0_w, skip0_b);

    int X = 0;   // layer-0 "X buffer" is virtual (affine of g_inp)
    int LIN = 19;
    for (int li = 0; li < 3; ++li) {
        int LOUT = LIN - 6;
        int Pp = 1000 * LIN;
        int li0 = (li == 0) ? 1 : 0;
        int hb[4], hn = 0;
        for (int b = 0; b < 6 && hn < 4; ++b)
            if (b != X && b != 1) hb[hn++] = b;
        int h1 = hb[0], h2 = hb[1], h3 = hb[2], h4 = hb[3];
        int CH = 32 * LIN;
        dim3 gg((unsigned)(CH / 4), NBC);

        // all 4 hops in one launch: o1=P1, o2=P2, o3=Q1, o4=Q2
        k_prop4<<<gg, 512, 0, stream>>>(X, h1, h2, h3, h4, li, CH, li0, start_w, start_b);

        k_mix<<<dim3((Pp + 255) / 256, NBC), 256, 0, stream>>>(X, h1, h2, h3, h4, 1,
            g1_w + li * 3072, g2_w + li * 3072, g1_b + li * 32, g2_b + li * 32, Pp,
            li0, start_w, start_b);

        int XG = h1;
        if (LIN == 19)
            k_incept<19><<<dim3(125, NBC), 256, 0, stream>>>(1, XG, X,
                filt_w[0] + li * 512, filt_w[1] + li * 768, filt_w[2] + li * 1536, filt_w[3] + li * 1792,
                filt_b + li * 32,
                gate_w[0] + li * 512, gate_w[1] + li * 768, gate_w[2] + li * 1536, gate_w[3] + li * 1792,
                gate_b + li * 32, skw[li], skb[li], li, li0, start_w, start_b);
        else if (LIN == 13)
            k_incept<13><<<dim3(125, NBC), 256, 0, stream>>>(1, XG, X,
                filt_w[0] + li * 512, filt_w[1] + li * 768, filt_w[2] + li * 1536, filt_w[3] + li * 1792,
                filt_b + li * 32,
                gate_w[0] + li * 512, gate_w[1] + li * 768, gate_w[2] + li * 1536, gate_w[3] + li * 1792,
                gate_b + li * 32, skw[li], skb[li], li, li0, start_w, start_b);
        else
            k_incept<7><<<dim3(125, NBC), 256, 0, stream>>>(1, XG, X,
                filt_w[0] + li * 512, filt_w[1] + li * 768, filt_w[2] + li * 1536, filt_w[3] + li * 1792,
                filt_b + li * 32,
                gate_w[0] + li * 512, gate_w[1] + li * 768, gate_w[2] + li * 1536, gate_w[3] + li * 1792,
                gate_b + li * 32, skw[li], skb[li], li, li0, start_w, start_b);

        k_norm<<<2048, 256, 0, stream>>>(XG, nww[li], nbb[li], li, LOUT);

        X = XG;
        LIN = LOUT;
    }
    k_final<<<dim3(63, NBC), 256, 0, stream>>>(X, skipE_w, skipE_b,
                                               end1_w, end1_b, end2_w, end2_b, outp);
}